// Round 15
// baseline (167.295 us; speedup 1.0000x reference)
//
#include <hip/hip_runtime.h>
#include <hip/hip_bf16.h>
#include <cstddef>

typedef __attribute__((ext_vector_type(8))) short s8v;
typedef __attribute__((ext_vector_type(4))) float f32x4;

// ---------------- L1: merged small repacks: W34 (288), w1b (24576), w8b (7168) ----------------
__global__ void fuse_small(const float* __restrict__ w3, const float* __restrict__ w4,
                           const float* __restrict__ w1, const float* __restrict__ w8,
                           float* __restrict__ W34, __hip_bfloat16* __restrict__ w1b,
                           __hip_bfloat16* __restrict__ w8b) {
    int idx = blockIdx.x * blockDim.x + threadIdx.x;
    if (idx < 288) {
        int ci = idx / 9, k1 = (idx / 3) % 3, k2 = idx % 3;
        float s = 0.f;
        for (int co = 0; co < 256; ++co)
            s += w3[(co * 32 + ci) * 3 + k1] * w4[co * 3 + k2];
        W34[idx] = s;
    }
    int i1 = idx - 512;
    if (i1 >= 0 && i1 < 24576) {
        int j = i1 & 7, co = (i1 >> 3) & 31, h = (i1 >> 8) & 3, c = (i1 >> 10) & 7, k = i1 >> 13;
        int ci = c * 32 + h * 8 + j;
        w1b[i1] = __float2bfloat16(w1[(co * 256 + ci) * 3 + k]);
    }
    int i2 = idx - 25600;
    if (i2 >= 0 && i2 < 7168) {
        int jj = i2 & 7, co = (i2 >> 3) & 31, h = (i2 >> 8) & 3, j = i2 >> 10;
        w8b[i2] = __float2bfloat16(w8[co * 224 + (h * 8 + jj) * 7 + j]);
    }
}

// ---------------- L2: t1 MFMA + (concurrent) fuse_w1215b ----------------
// blocks [0,1792): t1 conv 256->32 (HBM-bound); blocks [1792,2464): Wfb weight
// GEMM (L2/VALU-bound, depends only on w15/w12) -> runs in t1f's latency shadow.
__global__ __launch_bounds__(256) void k_t1fw(const float* __restrict__ x,
                                              const unsigned short* __restrict__ w1b,
                                              const float* __restrict__ w15,
                                              const float* __restrict__ w12,
                                              float* __restrict__ t1,
                                              __hip_bfloat16* __restrict__ Wfb) {
    __shared__ __align__(16) char lds[35840];
    const int t = threadIdx.x, b = blockIdx.x;

    if (b >= 1792) {  // ---- fuse_w1215b role: LDS-staged w12, conflict-free reads ----
        int bb = b - 1792;           // 0..671
        int kk = bb >> 5;            // 0..20
        int oct = bb & 31;
        int dy = kk / 7, dx = kk - dy * 7;
        int ci = t & 31, col = t >> 5;
        int co = oct * 8 + col;
        float* w12s = (float*)lds;   // [16 m][32 ci][7 dx] = 3584 f32
        float s = 0.f;
        for (int c = 0; c < 16; ++c) {
            const float4* src = (const float4*)(w12 + c * 3584);
            for (int u = t; u < 896; u += 256)
                ((float4*)w12s)[u] = src[u];
            __syncthreads();
            int mbase = c * 16;
#pragma unroll
            for (int m = 0; m < 16; ++m) {
                float a = w15[co * 768 + (mbase + m) * 3 + dy];
                s += a * w12s[(m * 32 + ci) * 7 + dx];
            }
            __syncthreads();
        }
        Wfb[(size_t)kk * 8192 + co * 32 + ci] = __float2bfloat16(s);
        return;
    }

    // ---- t1f role ----
    const int n = b / 56, y = b % 56;
    const int w = t >> 6, l = t & 63, h = l >> 4, q = l & 15;
    const float* xr = x + (size_t)(n * 256) * 3136 + y * 56;

#pragma unroll
    for (int it = 0; it < 2; ++it) {
        int u = it * 256 + t;
        if (u < 448) {
            int pi = u >> 5, g = u & 31;
            int pos = (pi < 3) ? pi : (56 + pi);
            *reinterpret_cast<s8v*>(lds + pos * 512 + ((g ^ (pos & 15)) << 4)) = (s8v)0;
        }
    }
#pragma unroll 2
    for (int it = 0; it < 7; ++it) {
        int u = it * 256 + t;
        int c2 = u / 14, xq = u % 14;
        int ci = c2 * 2;
        float4 a = *(const float4*)(xr + (size_t)ci * 3136 + xq * 4);
        float4 bv = *(const float4*)(xr + (size_t)(ci + 1) * 3136 + xq * 4);
        int g = ci >> 3, lo = (ci & 7) * 2;
#pragma unroll
        for (int j = 0; j < 4; ++j) {
            int pos = xq * 4 + j + 3;
            __hip_bfloat16 b0 = __float2bfloat16(((const float*)&a)[j]);
            __hip_bfloat16 b1 = __float2bfloat16(((const float*)&bv)[j]);
            unsigned int wd = (unsigned int)(*(unsigned short*)&b0) |
                              ((unsigned int)(*(unsigned short*)&b1) << 16);
            *(unsigned int*)(lds + pos * 512 + ((g ^ (pos & 15)) << 4) + lo) = wd;
        }
    }
    __syncthreads();

    f32x4 acc[2];
    acc[0] = (f32x4)0.f;
    acc[1] = (f32x4)0.f;

    for (int c = 0; c < 8; ++c) {
        const int g = c * 4 + h;
#pragma unroll
        for (int k = 0; k < 3; ++k) {
            s8v af[2];
#pragma unroll
            for (int m = 0; m < 2; ++m)
                af[m] = *reinterpret_cast<const s8v*>(
                    w1b + (size_t)((((k * 8 + c) * 4 + h) * 32 + m * 16 + q) * 8));
            int pos = w * 16 + q + 3 * k;
            s8v bf = *reinterpret_cast<const s8v*>(lds + pos * 512 + ((g ^ (pos & 15)) << 4));
            acc[0] = __builtin_amdgcn_mfma_f32_16x16x32_bf16(af[0], bf, acc[0], 0, 0, 0);
            acc[1] = __builtin_amdgcn_mfma_f32_16x16x32_bf16(af[1], bf, acc[1], 0, 0, 0);
        }
    }

    int px = w * 16 + q;
    if (px < 56) {
#pragma unroll
        for (int m = 0; m < 2; ++m)
#pragma unroll
            for (int r = 0; r < 4; ++r)
                t1[((size_t)(n * 32 + m * 16 + h * 4 + r) * 56 + y) * 56 + px] = acc[m][r];
    }
}

// ---------------- L3: merged mid kernel: t58 + t4 ----------------
// blocks [0,1792): t5+t8 MFMA -> t8T (XCD-swizzled);
// [1792,2240): t4 (XCD-swizzled).
__global__ __launch_bounds__(256) void k_mid(const float* __restrict__ t1,
                                             const float* __restrict__ p2w,
                                             const float* __restrict__ w5,
                                             const unsigned short* __restrict__ w8b,
                                             const float* __restrict__ W34,
                                             char* __restrict__ t8T,
                                             float* __restrict__ t4) {
    __shared__ __align__(16) char lds[9344];
    const int t = threadIdx.x, b = blockIdx.x;

    if (b >= 1792) {  // ---- t4 role (XCD-swizzled: 448 = 8 x 56) ----
        int by = b - 1792;
        int v4 = (by & 7) * 56 + (by >> 3);
        int n = v4 / 14;
        int y = (v4 % 14) * 4 + (t >> 6);
        int px = t & 63;
        if (px >= 56) return;
        float acc = 0.f;
#pragma unroll 4
        for (int ci = 0; ci < 32; ++ci) {
#pragma unroll
            for (int k1 = 0; k1 < 3; ++k1) {
                int yy = y + 2 * k1 - 2;
                if (yy < 0 || yy >= 56) continue;
                const float* r = t1 + ((size_t)(n * 32 + ci) * 56 + yy) * 56;
#pragma unroll
                for (int k2 = 0; k2 < 3; ++k2) {
                    int xx = px + 3 * k2 - 3;
                    if (xx >= 0 && xx < 56)
                        acc += r[xx] * W34[ci * 9 + k1 * 3 + k2];
                }
            }
        }
        t4[(size_t)(n * 56 + y) * 56 + px] = acc;
        return;
    }

    // ---- t5+t8 MFMA role (XCD-swizzled: 1792 = 8 x 224) ----
    const int v = (b & 7) * 224 + (b >> 3);
    const int n = v / 56, y = v % 56;
    const int w = t >> 6, l = t & 63, h = l >> 4, q = l & 15;
    const float* t1b = t1 + (size_t)(n * 32) * 3136;
    char* rowbuf = lds + 4864;

    if (t < 80) {
        int ph = t >> 2, g = t & 3;
        int pos = (ph < 6) ? ph : (56 + ph);
        *reinterpret_cast<s8v*>(lds + pos * 64 + ((g ^ ((pos >> 1) & 3)) << 4)) = (s8v)0;
    }
    if (t >= 80 && t < 136) {
        int u = t - 80;
        int ph = u >> 2, g = u & 3;
        int pos = (ph < 3) ? ph : (56 + ph);
        *reinterpret_cast<s8v*>(rowbuf + pos * 64 + ((g ^ ((pos >> 1) & 3)) << 4)) = (s8v)0;
    }
#pragma unroll
    for (int it = 0; it < 2; ++it) {
        int u = it * 256 + t;
        if (u < 448) {
            int ci = u / 14, xq = u % 14;
            float sc = p2w[ci];
            float4 s = {0.f, 0.f, 0.f, 0.f};
#pragma unroll
            for (int k = 0; k < 3; ++k) {
                int yy = y + 3 * k - 3;
                if (yy < 0 || yy >= 56) continue;
                float wv = w5[ci * 3 + k] * sc;
                float4 vv = *(const float4*)(t1b + (size_t)ci * 3136 + yy * 56 + xq * 4);
                s.x += wv * vv.x; s.y += wv * vv.y; s.z += wv * vv.z; s.w += wv * vv.w;
            }
            int g = ci >> 3, lo = (ci & 7) * 2;
#pragma unroll
            for (int j = 0; j < 4; ++j) {
                int pos = xq * 4 + j + 6;
                __hip_bfloat16 bv = __float2bfloat16(((const float*)&s)[j]);
                *(unsigned short*)(lds + pos * 64 + ((g ^ ((pos >> 1) & 3)) << 4) + lo) =
                    *(unsigned short*)&bv;
            }
        }
    }
    __syncthreads();

    f32x4 acc[2];
    acc[0] = (f32x4)0.f; acc[1] = (f32x4)0.f;
#pragma unroll
    for (int j = 0; j < 7; ++j) {
        s8v af[2];
#pragma unroll
        for (int m = 0; m < 2; ++m)
            af[m] = *reinterpret_cast<const s8v*>(
                w8b + (size_t)(((j * 4 + h) * 32 + m * 16 + q) * 8));
        int pos = w * 16 + q + 2 * j;
        s8v bf = *reinterpret_cast<const s8v*>(lds + pos * 64 + ((h ^ ((pos >> 1) & 3)) << 4));
        acc[0] = __builtin_amdgcn_mfma_f32_16x16x32_bf16(af[0], bf, acc[0], 0, 0, 0);
        acc[1] = __builtin_amdgcn_mfma_f32_16x16x32_bf16(af[1], bf, acc[1], 0, 0, 0);
    }

    int xx = w * 16 + q;
    if (xx < 56) {
        int pos = xx + 3;
#pragma unroll
        for (int m = 0; m < 2; ++m) {
#pragma unroll
            for (int r = 0; r < 4; ++r) {
                int co = m * 16 + h * 4 + r;
                __hip_bfloat16 bv = __float2bfloat16(acc[m][r]);
                *(unsigned short*)(rowbuf + pos * 64 + (((co >> 3) ^ ((pos >> 1) & 3)) << 4) +
                                   (co & 7) * 2) = *(unsigned short*)&bv;
            }
        }
    }
    __syncthreads();
    char* rowo = t8T + (size_t)(n * 56 + y) * 4480;
    for (int u = t; u < 280; u += 256)
        *reinterpret_cast<s8v*>(rowo + u * 16) = *reinterpret_cast<const s8v*>(rowbuf + u * 16);
}

// ---------------- L4: t8T -> t15 -> t16 + (pool->t11->t14 from t4) -> out ----------------
// grid 1792 (XCD-swizzled), block 512 = 8 waves, 1 row/block, wave = 32-co slice.
// Static fully-unrolled K-loop (zero-filled OOB dy rows).
__global__ __launch_bounds__(512) void k_t15r(const char* __restrict__ t8T,
                                              const unsigned short* __restrict__ Wfb,
                                              const float* __restrict__ w16,
                                              const float* __restrict__ w14,
                                              const float* __restrict__ t4,
                                              float* __restrict__ out) {
    __shared__ __align__(16) char lds[18816];
    float* Rr   = (float*)(lds + 13440);  // [5][64]
    float* Tt   = (float*)(lds + 14720);  // [3][64]
    float* t14l = (float*)(lds + 15488);  // [64]
    float* w16l = (float*)(lds + 15744);  // [768]
    const int t = threadIdx.x;
    const int b = blockIdx.x;
    const int vb = (b & 7) * 224 + (b >> 3);
    const int n = vb / 56, y = vb % 56;
    const int l = t & 63, h = l >> 4, q = l & 15;
    const int w = t >> 6;
    const int co0 = w * 32;
    const float* t4b = t4 + (size_t)n * 3136;

    // ---- stage 3 t8T rows y-2, y, y+2 (ridx = dy); zero-fill OOB rows ----
    for (int e = t; e < 840; e += 512) {
        int ridx = e / 280, u = e - ridx * 280;
        int yy = y + 2 * ridx - 2;
        s8v v = (s8v)0;
        if (yy >= 0 && yy < 56)
            v = *reinterpret_cast<const s8v*>(t8T + (size_t)(n * 56 + yy) * 4480 + u * 16);
        *reinterpret_cast<s8v*>(lds + ridx * 4480 + u * 16) = v;
    }
    // ---- w16 preload ----
    for (int e = t; e < 768; e += 512) w16l[e] = w16[e];
    // ---- pool pass 1: R rows yc = y-2 .. y+2 ----
    for (int e = t; e < 280; e += 512) {
        int ridx = e / 56, xx = e % 56;
        int yc = y - 2 + ridx;
        float rv = 0.f;
        if (yc >= 0 && yc < 56) {
            float mm = -3.4e38f;
#pragma unroll
            for (int i = 0; i < 7; ++i) {
                int yy = yc + 3 * i - 9;
                float v = (yy >= 0 && yy < 56) ? t4b[(size_t)yy * 56 + xx] : 0.f;
                mm = fmaxf(mm, v);
            }
            rv = fmaxf(mm, 0.f);
        }
        Rr[ridx * 64 + xx] = rv;
    }
    __syncthreads();
    // ---- pool pass 2: T (t11) rows yt = y-1 .. y+1 ----
    for (int e = t; e < 168; e += 512) {
        int ti = e / 56, px = e % 56;
        int yt = y - 1 + ti;
        float s = 0.f;
        if (yt >= 0 && yt < 56) {
#pragma unroll
            for (int dy = 0; dy < 3; ++dy) {
                int yr = yt + dy - 1;
                if (yr < 0 || yr >= 56) continue;
                int row = ti + dy;  // = yr - (y-2)
#pragma unroll
                for (int j = 0; j < 7; ++j) {
                    int xx = px + 3 * j - 9;
                    if (xx >= 0 && xx < 56) s += Rr[row * 64 + xx];
                }
            }
            s *= (1.f / 21.f);
        }
        Tt[ti * 64 + px] = s;
    }
    __syncthreads();
    // ---- pool pass 3: t14 row y ----
    if (t < 56) {
        int px = t;
        float s = 0.f;
#pragma unroll
        for (int dy = 0; dy < 3; ++dy) {
            int yy = y + dy - 1;
            if (yy < 0 || yy >= 56) continue;
#pragma unroll
            for (int dx = 0; dx < 3; ++dx) {
                int xx = px + dx - 1;
                if (xx < 0 || xx >= 56) continue;
                s += Tt[dy * 64 + xx] * w14[dy * 3 + dx];
            }
        }
        t14l[px] = s;
    }
    __syncthreads();

    f32x4 acc[2][4];
#pragma unroll
    for (int m = 0; m < 2; ++m)
#pragma unroll
        for (int nt = 0; nt < 4; ++nt)
            acc[m][nt] = (f32x4)0.f;

    // ---- fully static unrolled K-loop: 21 kk ----
#pragma unroll
    for (int dy = 0; dy < 3; ++dy) {
        const char* bbase = lds + dy * 4480;
#pragma unroll
        for (int dx = 0; dx < 7; ++dx) {
            const int kk = dy * 7 + dx;
            s8v af[2];
#pragma unroll
            for (int m = 0; m < 2; ++m)
                af[m] = *reinterpret_cast<const s8v*>(
                    Wfb + (size_t)kk * 8192 + (co0 + m * 16 + q) * 32 + h * 8);
            s8v bf[4];
#pragma unroll
            for (int nt = 0; nt < 4; ++nt) {
                int xp = nt * 16 + q + dx;
                bf[nt] = *reinterpret_cast<const s8v*>(
                    bbase + xp * 64 + ((h ^ ((xp >> 1) & 3)) << 4));
            }
#pragma unroll
            for (int nt = 0; nt < 4; ++nt)
#pragma unroll
                for (int m = 0; m < 2; ++m)
                    acc[m][nt] =
                        __builtin_amdgcn_mfma_f32_16x16x32_bf16(af[m], bf[nt], acc[m][nt], 0, 0, 0);
        }
    }

    // ---- t16 + t14 epilogue: in-register x+-3 via shuffles, coalesced stores ----
    float t14v[4];
#pragma unroll
    for (int nt = 0; nt < 4; ++nt) {
        int xx = nt * 16 + q;
        t14v[nt] = (xx < 56) ? t14l[xx] : 0.f;
    }
    const int srcm = (l & 48) | ((q + 13) & 15);
    const int srcp = (l & 48) | ((q + 3) & 15);
#pragma unroll
    for (int m = 0; m < 2; ++m) {
#pragma unroll
        for (int r = 0; r < 4; ++r) {
            int co = co0 + m * 16 + h * 4 + r;
            float wa = w16l[co * 3], wb = w16l[co * 3 + 1], wc = w16l[co * 3 + 2];
            float v[4], rm[4], rp[4];
#pragma unroll
            for (int nt = 0; nt < 4; ++nt) v[nt] = acc[m][nt][r];
#pragma unroll
            for (int nt = 0; nt < 4; ++nt) {
                rm[nt] = __shfl(v[nt], srcm, 64);
                rp[nt] = __shfl(v[nt], srcp, 64);
            }
            float* orow = out + ((size_t)(n * 256 + co) * 56 + y) * 56;
#pragma unroll
            for (int nt = 0; nt < 4; ++nt) {
                int xx = nt * 16 + q;
                float vm = (q >= 3) ? rm[nt] : (nt > 0 ? rm[nt - 1] : 0.f);
                float vp = (q < 13) ? rp[nt] : (nt < 3 ? rp[nt + 1] : 0.f);
                float s = v[nt] * wb + t14v[nt];
                s += (xx >= 3) ? vm * wa : 0.f;
                s += (xx <= 52) ? vp * wc : 0.f;
                if (xx < 56) orow[xx] = s;
            }
        }
    }
}

extern "C" void kernel_launch(void* const* d_in, const int* in_sizes, int n_in,
                              void* d_out, int out_size, void* d_ws, size_t ws_size,
                              hipStream_t stream) {
    const float* x   = (const float*)d_in[0];
    const float* w1  = (const float*)d_in[1];
    const float* p2w = (const float*)d_in[2];
    const float* w3  = (const float*)d_in[3];
    const float* w4  = (const float*)d_in[4];
    const float* w5  = (const float*)d_in[5];
    const float* w8  = (const float*)d_in[6];
    const float* w12 = (const float*)d_in[7];
    const float* w14 = (const float*)d_in[8];
    const float* w15 = (const float*)d_in[9];
    const float* w16 = (const float*)d_in[10];
    float* out = (float*)d_out;

    float* ws = (float*)d_ws;
    float* t1   = ws;                      // 3211264 f32
    char*  t8T  = (char*)(t1 + 3211264);   // 8,028,160 B
    float* t4   = t1 + 2 * 3211264;        // 100352 f32
    float* W34  = t4 + 100352;             // 288 f32
    __hip_bfloat16* Wfb = (__hip_bfloat16*)(W34 + 288);   // 172032 bf16
    __hip_bfloat16* w1b = Wfb + 172032;                   // 24576 bf16
    __hip_bfloat16* w8b = w1b + 24576;                    // 7168 bf16

    fuse_small<<<128, 256, 0, stream>>>(w3, w4, w1, w8, W34, w1b, w8b);
    k_t1fw<<<2464, 256, 0, stream>>>(x, (const unsigned short*)w1b, w15, w12, t1, Wfb);
    k_mid<<<2240, 256, 0, stream>>>(t1, p2w, w5, (const unsigned short*)w8b, W34, t8T, t4);
    k_t15r<<<1792, 512, 0, stream>>>(t8T, (const unsigned short*)Wfb, w16, w14, t4, out);
}

// Round 16
// 157.694 us; speedup vs baseline: 1.0609x; 1.0609x over previous
//
#include <hip/hip_runtime.h>
#include <hip/hip_bf16.h>
#include <cstddef>

typedef __attribute__((ext_vector_type(8))) short s8v;
typedef __attribute__((ext_vector_type(4))) float f32x4;

// ---------------- L1: merged small repacks: W34 (288), w1b (24576), w8b (7168) ----------------
__global__ void fuse_small(const float* __restrict__ w3, const float* __restrict__ w4,
                           const float* __restrict__ w1, const float* __restrict__ w8,
                           float* __restrict__ W34, __hip_bfloat16* __restrict__ w1b,
                           __hip_bfloat16* __restrict__ w8b) {
    int idx = blockIdx.x * blockDim.x + threadIdx.x;
    if (idx < 288) {
        int ci = idx / 9, k1 = (idx / 3) % 3, k2 = idx % 3;
        float s = 0.f;
        for (int co = 0; co < 256; ++co)
            s += w3[(co * 32 + ci) * 3 + k1] * w4[co * 3 + k2];
        W34[idx] = s;
    }
    int i1 = idx - 512;
    if (i1 >= 0 && i1 < 24576) {
        int j = i1 & 7, co = (i1 >> 3) & 31, h = (i1 >> 8) & 3, c = (i1 >> 10) & 7, k = i1 >> 13;
        int ci = c * 32 + h * 8 + j;
        w1b[i1] = __float2bfloat16(w1[(co * 256 + ci) * 3 + k]);
    }
    int i2 = idx - 25600;
    if (i2 >= 0 && i2 < 7168) {
        int jj = i2 & 7, co = (i2 >> 3) & 31, h = (i2 >> 8) & 3, j = i2 >> 10;
        w8b[i2] = __float2bfloat16(w8[co * 224 + (h * 8 + jj) * 7 + j]);
    }
}

// ---------------- L2: t1 fused MFMA: conv 256->32, 3 w-taps dil 3 ----------------
// grid 1792 (n,y), block 256 = 4 waves. Staging: ALL 14 float4 loads issued
// into registers first (deep MLP, hides HBM latency), then 56 cvt+pack b32
// LDS writes. Wave w owns px quarter, full K, barrier-free.
__global__ __launch_bounds__(256) void k_t1f(const float* __restrict__ x,
                                             const unsigned short* __restrict__ w1b,
                                             float* __restrict__ t1) {
    __shared__ __align__(16) char lds[35840];
    const int t = threadIdx.x, b = blockIdx.x;
    const int n = b / 56, y = b % 56;
    const int w = t >> 6, l = t & 63, h = l >> 4, q = l & 15;
    const float* xr = x + (size_t)(n * 256) * 3136 + y * 56;

    // ---- halo zeros: pos {0,1,2,59..69} x 32 g ----
#pragma unroll
    for (int it = 0; it < 2; ++it) {
        int u = it * 256 + t;
        if (u < 448) {
            int pi = u >> 5, g = u & 31;
            int pos = (pi < 3) ? pi : (56 + pi);
            *reinterpret_cast<s8v*>(lds + pos * 512 + ((g ^ (pos & 15)) << 4)) = (s8v)0;
        }
    }
    // ---- load batch: 14 independent float4 loads per lane ----
    float4 va[7], vb[7];
#pragma unroll
    for (int it = 0; it < 7; ++it) {
        int u = it * 256 + t;
        int c2 = u / 14, xq = u % 14;
        int ci = c2 * 2;
        va[it] = *(const float4*)(xr + (size_t)ci * 3136 + xq * 4);
        vb[it] = *(const float4*)(xr + (size_t)(ci + 1) * 3136 + xq * 4);
    }
    // ---- write batch: cvt + pack + b32 LDS writes ----
#pragma unroll
    for (int it = 0; it < 7; ++it) {
        int u = it * 256 + t;
        int c2 = u / 14, xq = u % 14;
        int ci = c2 * 2;
        int g = ci >> 3, lo = (ci & 7) * 2;
#pragma unroll
        for (int j = 0; j < 4; ++j) {
            int pos = xq * 4 + j + 3;
            __hip_bfloat16 b0 = __float2bfloat16(((const float*)&va[it])[j]);
            __hip_bfloat16 b1 = __float2bfloat16(((const float*)&vb[it])[j]);
            unsigned int wd = (unsigned int)(*(unsigned short*)&b0) |
                              ((unsigned int)(*(unsigned short*)&b1) << 16);
            *(unsigned int*)(lds + pos * 512 + ((g ^ (pos & 15)) << 4) + lo) = wd;
        }
    }
    __syncthreads();

    f32x4 acc[2];
    acc[0] = (f32x4)0.f;
    acc[1] = (f32x4)0.f;

    for (int c = 0; c < 8; ++c) {
        const int g = c * 4 + h;
#pragma unroll
        for (int k = 0; k < 3; ++k) {
            s8v af[2];
#pragma unroll
            for (int m = 0; m < 2; ++m)
                af[m] = *reinterpret_cast<const s8v*>(
                    w1b + (size_t)((((k * 8 + c) * 4 + h) * 32 + m * 16 + q) * 8));
            int pos = w * 16 + q + 3 * k;
            s8v bf = *reinterpret_cast<const s8v*>(lds + pos * 512 + ((g ^ (pos & 15)) << 4));
            acc[0] = __builtin_amdgcn_mfma_f32_16x16x32_bf16(af[0], bf, acc[0], 0, 0, 0);
            acc[1] = __builtin_amdgcn_mfma_f32_16x16x32_bf16(af[1], bf, acc[1], 0, 0, 0);
        }
    }

    int px = w * 16 + q;
    if (px < 56) {
#pragma unroll
        for (int m = 0; m < 2; ++m)
#pragma unroll
            for (int r = 0; r < 4; ++r)
                t1[((size_t)(n * 32 + m * 16 + h * 4 + r) * 56 + y) * 56 + px] = acc[m][r];
    }
}

// ---------------- L3: merged mid kernel ----------------
// blocks [0,1792): t5+t8 MFMA -> t8T (XCD-swizzled);
// [1792,2240): t4 (XCD-swizzled);  [2240,2912): fuse_w1215b (LDS-staged w12).
__global__ __launch_bounds__(256) void k_mid(const float* __restrict__ t1,
                                             const float* __restrict__ p2w,
                                             const float* __restrict__ w5,
                                             const unsigned short* __restrict__ w8b,
                                             const float* __restrict__ w15,
                                             const float* __restrict__ w12,
                                             const float* __restrict__ W34,
                                             char* __restrict__ t8T,
                                             __hip_bfloat16* __restrict__ Wfb,
                                             float* __restrict__ t4) {
    __shared__ __align__(16) char lds[14336];
    const int t = threadIdx.x, b = blockIdx.x;

    if (b >= 2240) {  // ---- fuse_w1215b role: LDS-staged w12, conflict-free reads ----
        int bb = b - 2240;           // 0..671
        int kk = bb >> 5;            // 0..20
        int oct = bb & 31;
        int dy = kk / 7, dx = kk - dy * 7;
        int ci = t & 31, col = t >> 5;
        int co = oct * 8 + col;
        float* w12s = (float*)lds;   // [16 m][32 ci][7 dx] = 3584 f32
        float s = 0.f;
        for (int c = 0; c < 16; ++c) {
            const float4* src = (const float4*)(w12 + c * 3584);
            for (int u = t; u < 896; u += 256)
                ((float4*)w12s)[u] = src[u];
            __syncthreads();
            int mbase = c * 16;
#pragma unroll
            for (int m = 0; m < 16; ++m) {
                float a = w15[co * 768 + (mbase + m) * 3 + dy];
                s += a * w12s[(m * 32 + ci) * 7 + dx];
            }
            __syncthreads();
        }
        Wfb[(size_t)kk * 8192 + co * 32 + ci] = __float2bfloat16(s);
        return;
    }
    if (b >= 1792) {  // ---- t4 role (XCD-swizzled: 448 = 8 x 56) ----
        int by = b - 1792;
        int v4 = (by & 7) * 56 + (by >> 3);
        int n = v4 / 14;
        int y = (v4 % 14) * 4 + (t >> 6);
        int px = t & 63;
        if (px >= 56) return;
        float acc = 0.f;
#pragma unroll 4
        for (int ci = 0; ci < 32; ++ci) {
#pragma unroll
            for (int k1 = 0; k1 < 3; ++k1) {
                int yy = y + 2 * k1 - 2;
                if (yy < 0 || yy >= 56) continue;
                const float* r = t1 + ((size_t)(n * 32 + ci) * 56 + yy) * 56;
#pragma unroll
                for (int k2 = 0; k2 < 3; ++k2) {
                    int xx = px + 3 * k2 - 3;
                    if (xx >= 0 && xx < 56)
                        acc += r[xx] * W34[ci * 9 + k1 * 3 + k2];
                }
            }
        }
        t4[(size_t)(n * 56 + y) * 56 + px] = acc;
        return;
    }

    // ---- t5+t8 MFMA role (XCD-swizzled: 1792 = 8 x 224) ----
    const int v = (b & 7) * 224 + (b >> 3);
    const int n = v / 56, y = v % 56;
    const int w = t >> 6, l = t & 63, h = l >> 4, q = l & 15;
    const float* t1b = t1 + (size_t)(n * 32) * 3136;
    char* rowbuf = lds + 4864;

    if (t < 80) {
        int ph = t >> 2, g = t & 3;
        int pos = (ph < 6) ? ph : (56 + ph);
        *reinterpret_cast<s8v*>(lds + pos * 64 + ((g ^ ((pos >> 1) & 3)) << 4)) = (s8v)0;
    }
    if (t >= 80 && t < 136) {
        int u = t - 80;
        int ph = u >> 2, g = u & 3;
        int pos = (ph < 3) ? ph : (56 + ph);
        *reinterpret_cast<s8v*>(rowbuf + pos * 64 + ((g ^ ((pos >> 1) & 3)) << 4)) = (s8v)0;
    }
#pragma unroll
    for (int it = 0; it < 2; ++it) {
        int u = it * 256 + t;
        if (u < 448) {
            int ci = u / 14, xq = u % 14;
            float sc = p2w[ci];
            float4 s = {0.f, 0.f, 0.f, 0.f};
#pragma unroll
            for (int k = 0; k < 3; ++k) {
                int yy = y + 3 * k - 3;
                if (yy < 0 || yy >= 56) continue;
                float wv = w5[ci * 3 + k] * sc;
                float4 vv = *(const float4*)(t1b + (size_t)ci * 3136 + yy * 56 + xq * 4);
                s.x += wv * vv.x; s.y += wv * vv.y; s.z += wv * vv.z; s.w += wv * vv.w;
            }
            int g = ci >> 3, lo = (ci & 7) * 2;
#pragma unroll
            for (int j = 0; j < 4; ++j) {
                int pos = xq * 4 + j + 6;
                __hip_bfloat16 bv = __float2bfloat16(((const float*)&s)[j]);
                *(unsigned short*)(lds + pos * 64 + ((g ^ ((pos >> 1) & 3)) << 4) + lo) =
                    *(unsigned short*)&bv;
            }
        }
    }
    __syncthreads();

    f32x4 acc[2];
    acc[0] = (f32x4)0.f; acc[1] = (f32x4)0.f;
#pragma unroll
    for (int j = 0; j < 7; ++j) {
        s8v af[2];
#pragma unroll
        for (int m = 0; m < 2; ++m)
            af[m] = *reinterpret_cast<const s8v*>(
                w8b + (size_t)(((j * 4 + h) * 32 + m * 16 + q) * 8));
        int pos = w * 16 + q + 2 * j;
        s8v bf = *reinterpret_cast<const s8v*>(lds + pos * 64 + ((h ^ ((pos >> 1) & 3)) << 4));
        acc[0] = __builtin_amdgcn_mfma_f32_16x16x32_bf16(af[0], bf, acc[0], 0, 0, 0);
        acc[1] = __builtin_amdgcn_mfma_f32_16x16x32_bf16(af[1], bf, acc[1], 0, 0, 0);
    }

    int xx = w * 16 + q;
    if (xx < 56) {
        int pos = xx + 3;
#pragma unroll
        for (int m = 0; m < 2; ++m) {
#pragma unroll
            for (int r = 0; r < 4; ++r) {
                int co = m * 16 + h * 4 + r;
                __hip_bfloat16 bv = __float2bfloat16(acc[m][r]);
                *(unsigned short*)(rowbuf + pos * 64 + (((co >> 3) ^ ((pos >> 1) & 3)) << 4) +
                                   (co & 7) * 2) = *(unsigned short*)&bv;
            }
        }
    }
    __syncthreads();
    char* rowo = t8T + (size_t)(n * 56 + y) * 4480;
    for (int u = t; u < 280; u += 256)
        *reinterpret_cast<s8v*>(rowo + u * 16) = *reinterpret_cast<const s8v*>(rowbuf + u * 16);
}

// ---------------- L4: t8T -> t15 -> t16 + (pool->t11->t14 from t4) -> out ----------------
// grid 1792 (XCD-swizzled), block 512 = 8 waves, 1 row/block, wave = 32-co slice.
// Static fully-unrolled K-loop (zero-filled OOB dy rows).
__global__ __launch_bounds__(512) void k_t15r(const char* __restrict__ t8T,
                                              const unsigned short* __restrict__ Wfb,
                                              const float* __restrict__ w16,
                                              const float* __restrict__ w14,
                                              const float* __restrict__ t4,
                                              float* __restrict__ out) {
    __shared__ __align__(16) char lds[18816];
    float* Rr   = (float*)(lds + 13440);  // [5][64]
    float* Tt   = (float*)(lds + 14720);  // [3][64]
    float* t14l = (float*)(lds + 15488);  // [64]
    float* w16l = (float*)(lds + 15744);  // [768]
    const int t = threadIdx.x;
    const int b = blockIdx.x;
    const int vb = (b & 7) * 224 + (b >> 3);
    const int n = vb / 56, y = vb % 56;
    const int l = t & 63, h = l >> 4, q = l & 15;
    const int w = t >> 6;
    const int co0 = w * 32;
    const float* t4b = t4 + (size_t)n * 3136;

    // ---- stage 3 t8T rows y-2, y, y+2 (ridx = dy); zero-fill OOB rows ----
    for (int e = t; e < 840; e += 512) {
        int ridx = e / 280, u = e - ridx * 280;
        int yy = y + 2 * ridx - 2;
        s8v v = (s8v)0;
        if (yy >= 0 && yy < 56)
            v = *reinterpret_cast<const s8v*>(t8T + (size_t)(n * 56 + yy) * 4480 + u * 16);
        *reinterpret_cast<s8v*>(lds + ridx * 4480 + u * 16) = v;
    }
    // ---- w16 preload ----
    for (int e = t; e < 768; e += 512) w16l[e] = w16[e];
    // ---- pool pass 1: R rows yc = y-2 .. y+2 ----
    for (int e = t; e < 280; e += 512) {
        int ridx = e / 56, xx = e % 56;
        int yc = y - 2 + ridx;
        float rv = 0.f;
        if (yc >= 0 && yc < 56) {
            float mm = -3.4e38f;
#pragma unroll
            for (int i = 0; i < 7; ++i) {
                int yy = yc + 3 * i - 9;
                float v = (yy >= 0 && yy < 56) ? t4b[(size_t)yy * 56 + xx] : 0.f;
                mm = fmaxf(mm, v);
            }
            rv = fmaxf(mm, 0.f);
        }
        Rr[ridx * 64 + xx] = rv;
    }
    __syncthreads();
    // ---- pool pass 2: T (t11) rows yt = y-1 .. y+1 ----
    for (int e = t; e < 168; e += 512) {
        int ti = e / 56, px = e % 56;
        int yt = y - 1 + ti;
        float s = 0.f;
        if (yt >= 0 && yt < 56) {
#pragma unroll
            for (int dy = 0; dy < 3; ++dy) {
                int yr = yt + dy - 1;
                if (yr < 0 || yr >= 56) continue;
                int row = ti + dy;  // = yr - (y-2)
#pragma unroll
                for (int j = 0; j < 7; ++j) {
                    int xx = px + 3 * j - 9;
                    if (xx >= 0 && xx < 56) s += Rr[row * 64 + xx];
                }
            }
            s *= (1.f / 21.f);
        }
        Tt[ti * 64 + px] = s;
    }
    __syncthreads();
    // ---- pool pass 3: t14 row y ----
    if (t < 56) {
        int px = t;
        float s = 0.f;
#pragma unroll
        for (int dy = 0; dy < 3; ++dy) {
            int yy = y + dy - 1;
            if (yy < 0 || yy >= 56) continue;
#pragma unroll
            for (int dx = 0; dx < 3; ++dx) {
                int xx = px + dx - 1;
                if (xx < 0 || xx >= 56) continue;
                s += Tt[dy * 64 + xx] * w14[dy * 3 + dx];
            }
        }
        t14l[px] = s;
    }
    __syncthreads();

    f32x4 acc[2][4];
#pragma unroll
    for (int m = 0; m < 2; ++m)
#pragma unroll
        for (int nt = 0; nt < 4; ++nt)
            acc[m][nt] = (f32x4)0.f;

    // ---- fully static unrolled K-loop: 21 kk ----
#pragma unroll
    for (int dy = 0; dy < 3; ++dy) {
        const char* bbase = lds + dy * 4480;
#pragma unroll
        for (int dx = 0; dx < 7; ++dx) {
            const int kk = dy * 7 + dx;
            s8v af[2];
#pragma unroll
            for (int m = 0; m < 2; ++m)
                af[m] = *reinterpret_cast<const s8v*>(
                    Wfb + (size_t)kk * 8192 + (co0 + m * 16 + q) * 32 + h * 8);
            s8v bf[4];
#pragma unroll
            for (int nt = 0; nt < 4; ++nt) {
                int xp = nt * 16 + q + dx;
                bf[nt] = *reinterpret_cast<const s8v*>(
                    bbase + xp * 64 + ((h ^ ((xp >> 1) & 3)) << 4));
            }
#pragma unroll
            for (int nt = 0; nt < 4; ++nt)
#pragma unroll
                for (int m = 0; m < 2; ++m)
                    acc[m][nt] =
                        __builtin_amdgcn_mfma_f32_16x16x32_bf16(af[m], bf[nt], acc[m][nt], 0, 0, 0);
        }
    }

    // ---- t16 + t14 epilogue: in-register x+-3 via shuffles, coalesced stores ----
    float t14v[4];
#pragma unroll
    for (int nt = 0; nt < 4; ++nt) {
        int xx = nt * 16 + q;
        t14v[nt] = (xx < 56) ? t14l[xx] : 0.f;
    }
    const int srcm = (l & 48) | ((q + 13) & 15);
    const int srcp = (l & 48) | ((q + 3) & 15);
#pragma unroll
    for (int m = 0; m < 2; ++m) {
#pragma unroll
        for (int r = 0; r < 4; ++r) {
            int co = co0 + m * 16 + h * 4 + r;
            float wa = w16l[co * 3], wb = w16l[co * 3 + 1], wc = w16l[co * 3 + 2];
            float v[4], rm[4], rp[4];
#pragma unroll
            for (int nt = 0; nt < 4; ++nt) v[nt] = acc[m][nt][r];
#pragma unroll
            for (int nt = 0; nt < 4; ++nt) {
                rm[nt] = __shfl(v[nt], srcm, 64);
                rp[nt] = __shfl(v[nt], srcp, 64);
            }
            float* orow = out + ((size_t)(n * 256 + co) * 56 + y) * 56;
#pragma unroll
            for (int nt = 0; nt < 4; ++nt) {
                int xx = nt * 16 + q;
                float vm = (q >= 3) ? rm[nt] : (nt > 0 ? rm[nt - 1] : 0.f);
                float vp = (q < 13) ? rp[nt] : (nt < 3 ? rp[nt + 1] : 0.f);
                float s = v[nt] * wb + t14v[nt];
                s += (xx >= 3) ? vm * wa : 0.f;
                s += (xx <= 52) ? vp * wc : 0.f;
                if (xx < 56) orow[xx] = s;
            }
        }
    }
}

extern "C" void kernel_launch(void* const* d_in, const int* in_sizes, int n_in,
                              void* d_out, int out_size, void* d_ws, size_t ws_size,
                              hipStream_t stream) {
    const float* x   = (const float*)d_in[0];
    const float* w1  = (const float*)d_in[1];
    const float* p2w = (const float*)d_in[2];
    const float* w3  = (const float*)d_in[3];
    const float* w4  = (const float*)d_in[4];
    const float* w5  = (const float*)d_in[5];
    const float* w8  = (const float*)d_in[6];
    const float* w12 = (const float*)d_in[7];
    const float* w14 = (const float*)d_in[8];
    const float* w15 = (const float*)d_in[9];
    const float* w16 = (const float*)d_in[10];
    float* out = (float*)d_out;

    float* ws = (float*)d_ws;
    float* t1   = ws;                      // 3211264 f32
    char*  t8T  = (char*)(t1 + 3211264);   // 8,028,160 B
    float* t4   = t1 + 2 * 3211264;        // 100352 f32
    float* W34  = t4 + 100352;             // 288 f32
    __hip_bfloat16* Wfb = (__hip_bfloat16*)(W34 + 288);   // 172032 bf16
    __hip_bfloat16* w1b = Wfb + 172032;                   // 24576 bf16
    __hip_bfloat16* w8b = w1b + 24576;                    // 7168 bf16

    fuse_small<<<128, 256, 0, stream>>>(w3, w4, w1, w8, W34, w1b, w8b);
    k_t1f<<<1792, 256, 0, stream>>>(x, (const unsigned short*)w1b, t1);
    k_mid<<<2912, 256, 0, stream>>>(t1, p2w, w5, (const unsigned short*)w8b,
                                    w15, w12, W34, t8T, Wfb, t4);
    k_t15r<<<1792, 512, 0, stream>>>(t8T, (const unsigned short*)Wfb, w16, w14, t4, out);
}

// Round 17
// 157.669 us; speedup vs baseline: 1.0611x; 1.0002x over previous
//
#include <hip/hip_runtime.h>
#include <hip/hip_bf16.h>
#include <cstddef>

typedef __attribute__((ext_vector_type(8))) short s8v;
typedef __attribute__((ext_vector_type(4))) float f32x4;

// ---------------- L1: merged small repacks: W34 (288), w1b (24576), w8b (7168) ----------------
__global__ void fuse_small(const float* __restrict__ w3, const float* __restrict__ w4,
                           const float* __restrict__ w1, const float* __restrict__ w8,
                           float* __restrict__ W34, __hip_bfloat16* __restrict__ w1b,
                           __hip_bfloat16* __restrict__ w8b) {
    int idx = blockIdx.x * blockDim.x + threadIdx.x;
    if (idx < 288) {
        int ci = idx / 9, k1 = (idx / 3) % 3, k2 = idx % 3;
        float s = 0.f;
        for (int co = 0; co < 256; ++co)
            s += w3[(co * 32 + ci) * 3 + k1] * w4[co * 3 + k2];
        W34[idx] = s;
    }
    int i1 = idx - 512;
    if (i1 >= 0 && i1 < 24576) {
        int j = i1 & 7, co = (i1 >> 3) & 31, h = (i1 >> 8) & 3, c = (i1 >> 10) & 7, k = i1 >> 13;
        int ci = c * 32 + h * 8 + j;
        w1b[i1] = __float2bfloat16(w1[(co * 256 + ci) * 3 + k]);
    }
    int i2 = idx - 25600;
    if (i2 >= 0 && i2 < 7168) {
        int jj = i2 & 7, co = (i2 >> 3) & 31, h = (i2 >> 8) & 3, j = i2 >> 10;
        w8b[i2] = __float2bfloat16(w8[co * 224 + (h * 8 + jj) * 7 + j]);
    }
}

// ---------------- L2: t1 fused MFMA: conv 256->32, 3 w-taps dil 3 ----------------
// grid 1792 (n,y), block 256 = 4 waves. Load-batch staging; c-loop unroll 4 so
// the scheduler hoists independent w1b global loads across iterations.
__global__ __launch_bounds__(256) void k_t1f(const float* __restrict__ x,
                                             const unsigned short* __restrict__ w1b,
                                             float* __restrict__ t1) {
    __shared__ __align__(16) char lds[35840];
    const int t = threadIdx.x, b = blockIdx.x;
    const int n = b / 56, y = b % 56;
    const int w = t >> 6, l = t & 63, h = l >> 4, q = l & 15;
    const float* xr = x + (size_t)(n * 256) * 3136 + y * 56;

    // ---- halo zeros: pos {0,1,2,59..69} x 32 g ----
#pragma unroll
    for (int it = 0; it < 2; ++it) {
        int u = it * 256 + t;
        if (u < 448) {
            int pi = u >> 5, g = u & 31;
            int pos = (pi < 3) ? pi : (56 + pi);
            *reinterpret_cast<s8v*>(lds + pos * 512 + ((g ^ (pos & 15)) << 4)) = (s8v)0;
        }
    }
    // ---- load batch: 14 independent float4 loads per lane ----
    float4 va[7], vb[7];
#pragma unroll
    for (int it = 0; it < 7; ++it) {
        int u = it * 256 + t;
        int c2 = u / 14, xq = u % 14;
        int ci = c2 * 2;
        va[it] = *(const float4*)(xr + (size_t)ci * 3136 + xq * 4);
        vb[it] = *(const float4*)(xr + (size_t)(ci + 1) * 3136 + xq * 4);
    }
    // ---- write batch: cvt + pack + b32 LDS writes ----
#pragma unroll
    for (int it = 0; it < 7; ++it) {
        int u = it * 256 + t;
        int c2 = u / 14, xq = u % 14;
        int ci = c2 * 2;
        int g = ci >> 3, lo = (ci & 7) * 2;
#pragma unroll
        for (int j = 0; j < 4; ++j) {
            int pos = xq * 4 + j + 3;
            __hip_bfloat16 b0 = __float2bfloat16(((const float*)&va[it])[j]);
            __hip_bfloat16 b1 = __float2bfloat16(((const float*)&vb[it])[j]);
            unsigned int wd = (unsigned int)(*(unsigned short*)&b0) |
                              ((unsigned int)(*(unsigned short*)&b1) << 16);
            *(unsigned int*)(lds + pos * 512 + ((g ^ (pos & 15)) << 4) + lo) = wd;
        }
    }
    __syncthreads();

    f32x4 acc[2];
    acc[0] = (f32x4)0.f;
    acc[1] = (f32x4)0.f;

#pragma unroll 4
    for (int c = 0; c < 8; ++c) {
        const int g = c * 4 + h;
#pragma unroll
        for (int k = 0; k < 3; ++k) {
            s8v af[2];
#pragma unroll
            for (int m = 0; m < 2; ++m)
                af[m] = *reinterpret_cast<const s8v*>(
                    w1b + (size_t)((((k * 8 + c) * 4 + h) * 32 + m * 16 + q) * 8));
            int pos = w * 16 + q + 3 * k;
            s8v bf = *reinterpret_cast<const s8v*>(lds + pos * 512 + ((g ^ (pos & 15)) << 4));
            acc[0] = __builtin_amdgcn_mfma_f32_16x16x32_bf16(af[0], bf, acc[0], 0, 0, 0);
            acc[1] = __builtin_amdgcn_mfma_f32_16x16x32_bf16(af[1], bf, acc[1], 0, 0, 0);
        }
    }

    int px = w * 16 + q;
    if (px < 56) {
#pragma unroll
        for (int m = 0; m < 2; ++m)
#pragma unroll
            for (int r = 0; r < 4; ++r)
                t1[((size_t)(n * 32 + m * 16 + h * 4 + r) * 56 + y) * 56 + px] = acc[m][r];
    }
}

// ---------------- L3: merged mid kernel ----------------
// blocks [0,1792): t5+t8 MFMA -> t8T (XCD-swizzled);
// [1792,2240): t4 (XCD-swizzled);  [2240,2912): fuse_w1215b (LDS-staged w12).
__global__ __launch_bounds__(256) void k_mid(const float* __restrict__ t1,
                                             const float* __restrict__ p2w,
                                             const float* __restrict__ w5,
                                             const unsigned short* __restrict__ w8b,
                                             const float* __restrict__ w15,
                                             const float* __restrict__ w12,
                                             const float* __restrict__ W34,
                                             char* __restrict__ t8T,
                                             __hip_bfloat16* __restrict__ Wfb,
                                             float* __restrict__ t4) {
    __shared__ __align__(16) char lds[14336];
    const int t = threadIdx.x, b = blockIdx.x;

    if (b >= 2240) {  // ---- fuse_w1215b role: LDS-staged w12, conflict-free reads ----
        int bb = b - 2240;           // 0..671
        int kk = bb >> 5;            // 0..20
        int oct = bb & 31;
        int dy = kk / 7, dx = kk - dy * 7;
        int ci = t & 31, col = t >> 5;
        int co = oct * 8 + col;
        float* w12s = (float*)lds;   // [16 m][32 ci][7 dx] = 3584 f32
        float s = 0.f;
        for (int c = 0; c < 16; ++c) {
            const float4* src = (const float4*)(w12 + c * 3584);
            for (int u = t; u < 896; u += 256)
                ((float4*)w12s)[u] = src[u];
            __syncthreads();
            int mbase = c * 16;
#pragma unroll
            for (int m = 0; m < 16; ++m) {
                float a = w15[co * 768 + (mbase + m) * 3 + dy];
                s += a * w12s[(m * 32 + ci) * 7 + dx];
            }
            __syncthreads();
        }
        Wfb[(size_t)kk * 8192 + co * 32 + ci] = __float2bfloat16(s);
        return;
    }
    if (b >= 1792) {  // ---- t4 role (XCD-swizzled: 448 = 8 x 56) ----
        int by = b - 1792;
        int v4 = (by & 7) * 56 + (by >> 3);
        int n = v4 / 14;
        int y = (v4 % 14) * 4 + (t >> 6);
        int px = t & 63;
        if (px >= 56) return;
        float acc = 0.f;
#pragma unroll 4
        for (int ci = 0; ci < 32; ++ci) {
#pragma unroll
            for (int k1 = 0; k1 < 3; ++k1) {
                int yy = y + 2 * k1 - 2;
                if (yy < 0 || yy >= 56) continue;
                const float* r = t1 + ((size_t)(n * 32 + ci) * 56 + yy) * 56;
#pragma unroll
                for (int k2 = 0; k2 < 3; ++k2) {
                    int xx = px + 3 * k2 - 3;
                    if (xx >= 0 && xx < 56)
                        acc += r[xx] * W34[ci * 9 + k1 * 3 + k2];
                }
            }
        }
        t4[(size_t)(n * 56 + y) * 56 + px] = acc;
        return;
    }

    // ---- t5+t8 MFMA role (XCD-swizzled: 1792 = 8 x 224) ----
    const int v = (b & 7) * 224 + (b >> 3);
    const int n = v / 56, y = v % 56;
    const int w = t >> 6, l = t & 63, h = l >> 4, q = l & 15;
    const float* t1b = t1 + (size_t)(n * 32) * 3136;
    char* rowbuf = lds + 4864;

    if (t < 80) {
        int ph = t >> 2, g = t & 3;
        int pos = (ph < 6) ? ph : (56 + ph);
        *reinterpret_cast<s8v*>(lds + pos * 64 + ((g ^ ((pos >> 1) & 3)) << 4)) = (s8v)0;
    }
    if (t >= 80 && t < 136) {
        int u = t - 80;
        int ph = u >> 2, g = u & 3;
        int pos = (ph < 3) ? ph : (56 + ph);
        *reinterpret_cast<s8v*>(rowbuf + pos * 64 + ((g ^ ((pos >> 1) & 3)) << 4)) = (s8v)0;
    }
#pragma unroll
    for (int it = 0; it < 2; ++it) {
        int u = it * 256 + t;
        if (u < 448) {
            int ci = u / 14, xq = u % 14;
            float sc = p2w[ci];
            float4 s = {0.f, 0.f, 0.f, 0.f};
#pragma unroll
            for (int k = 0; k < 3; ++k) {
                int yy = y + 3 * k - 3;
                if (yy < 0 || yy >= 56) continue;
                float wv = w5[ci * 3 + k] * sc;
                float4 vv = *(const float4*)(t1b + (size_t)ci * 3136 + yy * 56 + xq * 4);
                s.x += wv * vv.x; s.y += wv * vv.y; s.z += wv * vv.z; s.w += wv * vv.w;
            }
            int g = ci >> 3, lo = (ci & 7) * 2;
#pragma unroll
            for (int j = 0; j < 4; ++j) {
                int pos = xq * 4 + j + 6;
                __hip_bfloat16 bv = __float2bfloat16(((const float*)&s)[j]);
                *(unsigned short*)(lds + pos * 64 + ((g ^ ((pos >> 1) & 3)) << 4) + lo) =
                    *(unsigned short*)&bv;
            }
        }
    }
    __syncthreads();

    f32x4 acc[2];
    acc[0] = (f32x4)0.f; acc[1] = (f32x4)0.f;
#pragma unroll
    for (int j = 0; j < 7; ++j) {
        s8v af[2];
#pragma unroll
        for (int m = 0; m < 2; ++m)
            af[m] = *reinterpret_cast<const s8v*>(
                w8b + (size_t)(((j * 4 + h) * 32 + m * 16 + q) * 8));
        int pos = w * 16 + q + 2 * j;
        s8v bf = *reinterpret_cast<const s8v*>(lds + pos * 64 + ((h ^ ((pos >> 1) & 3)) << 4));
        acc[0] = __builtin_amdgcn_mfma_f32_16x16x32_bf16(af[0], bf, acc[0], 0, 0, 0);
        acc[1] = __builtin_amdgcn_mfma_f32_16x16x32_bf16(af[1], bf, acc[1], 0, 0, 0);
    }

    int xx = w * 16 + q;
    if (xx < 56) {
        int pos = xx + 3;
#pragma unroll
        for (int m = 0; m < 2; ++m) {
#pragma unroll
            for (int r = 0; r < 4; ++r) {
                int co = m * 16 + h * 4 + r;
                __hip_bfloat16 bv = __float2bfloat16(acc[m][r]);
                *(unsigned short*)(rowbuf + pos * 64 + (((co >> 3) ^ ((pos >> 1) & 3)) << 4) +
                                   (co & 7) * 2) = *(unsigned short*)&bv;
            }
        }
    }
    __syncthreads();
    char* rowo = t8T + (size_t)(n * 56 + y) * 4480;
    for (int u = t; u < 280; u += 256)
        *reinterpret_cast<s8v*>(rowo + u * 16) = *reinterpret_cast<const s8v*>(rowbuf + u * 16);
}

// ---------------- L4: t8T -> t15 -> t16 + (pool->t11->t14 from t4) -> out ----------------
// grid 3584 (XCD-swizzled: 8 x 448), block 256 = 4 waves. Each block: one row y,
// co half [half*128, half*128+128); wave w -> co slice of 32. 14 blocks/CU ->
// smooth residency. Static fully-unrolled K-loop (zero-filled OOB dy rows).
__global__ __launch_bounds__(256) void k_t15s(const char* __restrict__ t8T,
                                              const unsigned short* __restrict__ Wfb,
                                              const float* __restrict__ w16,
                                              const float* __restrict__ w14,
                                              const float* __restrict__ t4,
                                              float* __restrict__ out) {
    __shared__ __align__(16) char lds[18816];
    float* Rr   = (float*)(lds + 13440);  // [5][64]
    float* Tt   = (float*)(lds + 14720);  // [3][64]
    float* t14l = (float*)(lds + 15488);  // [64]
    float* w16l = (float*)(lds + 15744);  // [768]
    const int t = threadIdx.x;
    const int b = blockIdx.x;
    const int vb = (b & 7) * 448 + (b >> 3);
    const int n = vb / 112;
    const int rem = vb % 112;
    const int y = rem >> 1, half = rem & 1;
    const int l = t & 63, h = l >> 4, q = l & 15;
    const int w = t >> 6;
    const int co0 = half * 128 + w * 32;
    const float* t4b = t4 + (size_t)n * 3136;

    // ---- stage 3 t8T rows y-2, y, y+2 (ridx = dy); zero-fill OOB rows ----
    for (int e = t; e < 840; e += 256) {
        int ridx = e / 280, u = e - ridx * 280;
        int yy = y + 2 * ridx - 2;
        s8v v = (s8v)0;
        if (yy >= 0 && yy < 56)
            v = *reinterpret_cast<const s8v*>(t8T + (size_t)(n * 56 + yy) * 4480 + u * 16);
        *reinterpret_cast<s8v*>(lds + ridx * 4480 + u * 16) = v;
    }
    // ---- w16 half preload (only this block's 128 co) ----
    for (int e = t; e < 384; e += 256) w16l[e] = w16[half * 384 + e];
    // ---- pool pass 1: R rows yc = y-2 .. y+2 ----
    for (int e = t; e < 280; e += 256) {
        int ridx = e / 56, xx = e % 56;
        int yc = y - 2 + ridx;
        float rv = 0.f;
        if (yc >= 0 && yc < 56) {
            float mm = -3.4e38f;
#pragma unroll
            for (int i = 0; i < 7; ++i) {
                int yy = yc + 3 * i - 9;
                float v = (yy >= 0 && yy < 56) ? t4b[(size_t)yy * 56 + xx] : 0.f;
                mm = fmaxf(mm, v);
            }
            rv = fmaxf(mm, 0.f);
        }
        Rr[ridx * 64 + xx] = rv;
    }
    __syncthreads();
    // ---- pool pass 2: T (t11) rows yt = y-1 .. y+1 ----
    for (int e = t; e < 168; e += 256) {
        int ti = e / 56, px = e % 56;
        int yt = y - 1 + ti;
        float s = 0.f;
        if (yt >= 0 && yt < 56) {
#pragma unroll
            for (int dy = 0; dy < 3; ++dy) {
                int yr = yt + dy - 1;
                if (yr < 0 || yr >= 56) continue;
                int row = ti + dy;  // = yr - (y-2)
#pragma unroll
                for (int j = 0; j < 7; ++j) {
                    int xx = px + 3 * j - 9;
                    if (xx >= 0 && xx < 56) s += Rr[row * 64 + xx];
                }
            }
            s *= (1.f / 21.f);
        }
        Tt[ti * 64 + px] = s;
    }
    __syncthreads();
    // ---- pool pass 3: t14 row y ----
    if (t < 56) {
        int px = t;
        float s = 0.f;
#pragma unroll
        for (int dy = 0; dy < 3; ++dy) {
            int yy = y + dy - 1;
            if (yy < 0 || yy >= 56) continue;
#pragma unroll
            for (int dx = 0; dx < 3; ++dx) {
                int xx = px + dx - 1;
                if (xx < 0 || xx >= 56) continue;
                s += Tt[dy * 64 + xx] * w14[dy * 3 + dx];
            }
        }
        t14l[px] = s;
    }
    __syncthreads();

    f32x4 acc[2][4];
#pragma unroll
    for (int m = 0; m < 2; ++m)
#pragma unroll
        for (int nt = 0; nt < 4; ++nt)
            acc[m][nt] = (f32x4)0.f;

    // ---- fully static unrolled K-loop: 21 kk ----
#pragma unroll
    for (int dy = 0; dy < 3; ++dy) {
        const char* bbase = lds + dy * 4480;
#pragma unroll
        for (int dx = 0; dx < 7; ++dx) {
            const int kk = dy * 7 + dx;
            s8v af[2];
#pragma unroll
            for (int m = 0; m < 2; ++m)
                af[m] = *reinterpret_cast<const s8v*>(
                    Wfb + (size_t)kk * 8192 + (co0 + m * 16 + q) * 32 + h * 8);
            s8v bf[4];
#pragma unroll
            for (int nt = 0; nt < 4; ++nt) {
                int xp = nt * 16 + q + dx;
                bf[nt] = *reinterpret_cast<const s8v*>(
                    bbase + xp * 64 + ((h ^ ((xp >> 1) & 3)) << 4));
            }
#pragma unroll
            for (int nt = 0; nt < 4; ++nt)
#pragma unroll
                for (int m = 0; m < 2; ++m)
                    acc[m][nt] =
                        __builtin_amdgcn_mfma_f32_16x16x32_bf16(af[m], bf[nt], acc[m][nt], 0, 0, 0);
        }
    }

    // ---- t16 + t14 epilogue: in-register x+-3 via shuffles, coalesced stores ----
    float t14v[4];
#pragma unroll
    for (int nt = 0; nt < 4; ++nt) {
        int xx = nt * 16 + q;
        t14v[nt] = (xx < 56) ? t14l[xx] : 0.f;
    }
    const int srcm = (l & 48) | ((q + 13) & 15);
    const int srcp = (l & 48) | ((q + 3) & 15);
#pragma unroll
    for (int m = 0; m < 2; ++m) {
#pragma unroll
        for (int r = 0; r < 4; ++r) {
            int co = co0 + m * 16 + h * 4 + r;
            int cl = co - half * 128;  // index into w16l
            float wa = w16l[cl * 3], wb = w16l[cl * 3 + 1], wc = w16l[cl * 3 + 2];
            float v[4], rm[4], rp[4];
#pragma unroll
            for (int nt = 0; nt < 4; ++nt) v[nt] = acc[m][nt][r];
#pragma unroll
            for (int nt = 0; nt < 4; ++nt) {
                rm[nt] = __shfl(v[nt], srcm, 64);
                rp[nt] = __shfl(v[nt], srcp, 64);
            }
            float* orow = out + ((size_t)(n * 256 + co) * 56 + y) * 56;
#pragma unroll
            for (int nt = 0; nt < 4; ++nt) {
                int xx = nt * 16 + q;
                float vm = (q >= 3) ? rm[nt] : (nt > 0 ? rm[nt - 1] : 0.f);
                float vp = (q < 13) ? rp[nt] : (nt < 3 ? rp[nt + 1] : 0.f);
                float s = v[nt] * wb + t14v[nt];
                s += (xx >= 3) ? vm * wa : 0.f;
                s += (xx <= 52) ? vp * wc : 0.f;
                if (xx < 56) orow[xx] = s;
            }
        }
    }
}

extern "C" void kernel_launch(void* const* d_in, const int* in_sizes, int n_in,
                              void* d_out, int out_size, void* d_ws, size_t ws_size,
                              hipStream_t stream) {
    const float* x   = (const float*)d_in[0];
    const float* w1  = (const float*)d_in[1];
    const float* p2w = (const float*)d_in[2];
    const float* w3  = (const float*)d_in[3];
    const float* w4  = (const float*)d_in[4];
    const float* w5  = (const float*)d_in[5];
    const float* w8  = (const float*)d_in[6];
    const float* w12 = (const float*)d_in[7];
    const float* w14 = (const float*)d_in[8];
    const float* w15 = (const float*)d_in[9];
    const float* w16 = (const float*)d_in[10];
    float* out = (float*)d_out;

    float* ws = (float*)d_ws;
    float* t1   = ws;                      // 3211264 f32
    char*  t8T  = (char*)(t1 + 3211264);   // 8,028,160 B
    float* t4   = t1 + 2 * 3211264;        // 100352 f32
    float* W34  = t4 + 100352;             // 288 f32
    __hip_bfloat16* Wfb = (__hip_bfloat16*)(W34 + 288);   // 172032 bf16
    __hip_bfloat16* w1b = Wfb + 172032;                   // 24576 bf16
    __hip_bfloat16* w8b = w1b + 24576;                    // 7168 bf16

    fuse_small<<<128, 256, 0, stream>>>(w3, w4, w1, w8, W34, w1b, w8b);
    k_t1f<<<1792, 256, 0, stream>>>(x, (const unsigned short*)w1b, t1);
    k_mid<<<2912, 256, 0, stream>>>(t1, p2w, w5, (const unsigned short*)w8b,
                                    w15, w12, W34, t8T, Wfb, t4);
    k_t15s<<<3584, 256, 0, stream>>>(t8T, (const unsigned short*)Wfb, w16, w14, t4, out);
}

// Round 18
// 149.512 us; speedup vs baseline: 1.1189x; 1.0546x over previous
//
#include <hip/hip_runtime.h>
#include <hip/hip_bf16.h>
#include <cstddef>

typedef __attribute__((ext_vector_type(8))) short s8v;
typedef __attribute__((ext_vector_type(4))) float f32x4;

// ---------------- L1: merged small repacks: W34 (288), w1b (24576), w8b (7168) ----------------
__global__ void fuse_small(const float* __restrict__ w3, const float* __restrict__ w4,
                           const float* __restrict__ w1, const float* __restrict__ w8,
                           float* __restrict__ W34, __hip_bfloat16* __restrict__ w1b,
                           __hip_bfloat16* __restrict__ w8b) {
    int idx = blockIdx.x * blockDim.x + threadIdx.x;
    if (idx < 288) {
        int ci = idx / 9, k1 = (idx / 3) % 3, k2 = idx % 3;
        float s = 0.f;
        for (int co = 0; co < 256; ++co)
            s += w3[(co * 32 + ci) * 3 + k1] * w4[co * 3 + k2];
        W34[idx] = s;
    }
    int i1 = idx - 512;
    if (i1 >= 0 && i1 < 24576) {
        int j = i1 & 7, co = (i1 >> 3) & 31, h = (i1 >> 8) & 3, c = (i1 >> 10) & 7, k = i1 >> 13;
        int ci = c * 32 + h * 8 + j;
        w1b[i1] = __float2bfloat16(w1[(co * 256 + ci) * 3 + k]);
    }
    int i2 = idx - 25600;
    if (i2 >= 0 && i2 < 7168) {
        int jj = i2 & 7, co = (i2 >> 3) & 31, h = (i2 >> 8) & 3, j = i2 >> 10;
        w8b[i2] = __float2bfloat16(w8[co * 224 + (h * 8 + jj) * 7 + j]);
    }
}

// ---------------- L2: t1 fused MFMA, y-pair blocks for 448B DRAM bursts ----------------
// grid 896 (n, ypair), block 512 = 8 waves. Rows y0,y0+1 contiguous in x ->
// each ci-plane read is 448B contiguous. Two B-tiles in LDS (71.7 KB, 2 blk/CU).
// Waves 0-3: row y0 px-quarters; waves 4-7: row y0+1. Full-K per wave, no
// post-stage barriers beyond the single __syncthreads.
__global__ __launch_bounds__(512) void k_t1f2(const float* __restrict__ x,
                                              const unsigned short* __restrict__ w1b,
                                              float* __restrict__ t1) {
    __shared__ __align__(16) char lds[71680];   // 2 x 35840
    const int t = threadIdx.x, b = blockIdx.x;
    const int vb = (b & 7) * 112 + (b >> 3);    // XCD-bijective (896 = 8 x 112)
    const int n = vb / 28, y0 = (vb % 28) * 2;
    const int w = t >> 6, l = t & 63, h = l >> 4, q = l & 15;
    const int rg = w >> 2, wq = w & 3;
    const int y = y0 + rg;
    const float* xr = x + (size_t)(n * 256) * 3136 + y0 * 56;  // + ci*3136 + 0..111

    // ---- halo zeros: both row-tiles, pos {0,1,2,59..69} x 32 g ----
#pragma unroll
    for (int it = 0; it < 2; ++it) {
        int e = it * 512 + t;
        if (e < 896) {
            int rt = e / 448, u = e % 448;
            int pi = u >> 5, g = u & 31;
            int pos = (pi < 3) ? pi : (56 + pi);
            *reinterpret_cast<s8v*>(lds + rt * 35840 + pos * 512 + ((g ^ (pos & 15)) << 4)) =
                (s8v)0;
        }
    }
    // ---- load batch: 3584 units (ci-pair, xq2 0..27); 14 float4/lane, 448B bursts ----
    float4 va[7], vb7[7];
#pragma unroll
    for (int it = 0; it < 7; ++it) {
        int u = it * 512 + t;
        int c2 = u / 28, xq2 = u % 28;
        int ci = c2 * 2;
        va[it]  = *(const float4*)(xr + (size_t)ci * 3136 + xq2 * 4);
        vb7[it] = *(const float4*)(xr + (size_t)(ci + 1) * 3136 + xq2 * 4);
    }
    // ---- write batch: cvt + pack + b32 LDS writes into row-tile rt ----
#pragma unroll
    for (int it = 0; it < 7; ++it) {
        int u = it * 512 + t;
        int c2 = u / 28, xq2 = u % 28;
        int ci = c2 * 2;
        int rt = (xq2 >= 14) ? 1 : 0;
        int xq = xq2 - rt * 14;
        int g = ci >> 3, lo = (ci & 7) * 2;
        char* base = lds + rt * 35840;
#pragma unroll
        for (int j = 0; j < 4; ++j) {
            int pos = xq * 4 + j + 3;
            __hip_bfloat16 b0 = __float2bfloat16(((const float*)&va[it])[j]);
            __hip_bfloat16 b1 = __float2bfloat16(((const float*)&vb7[it])[j]);
            unsigned int wd = (unsigned int)(*(unsigned short*)&b0) |
                              ((unsigned int)(*(unsigned short*)&b1) << 16);
            *(unsigned int*)(base + pos * 512 + ((g ^ (pos & 15)) << 4) + lo) = wd;
        }
    }
    __syncthreads();

    f32x4 acc[2];
    acc[0] = (f32x4)0.f;
    acc[1] = (f32x4)0.f;
    const char* bbase = lds + rg * 35840;

#pragma unroll 4
    for (int c = 0; c < 8; ++c) {
        const int g = c * 4 + h;
#pragma unroll
        for (int k = 0; k < 3; ++k) {
            s8v af[2];
#pragma unroll
            for (int m = 0; m < 2; ++m)
                af[m] = *reinterpret_cast<const s8v*>(
                    w1b + (size_t)((((k * 8 + c) * 4 + h) * 32 + m * 16 + q) * 8));
            int pos = wq * 16 + q + 3 * k;
            s8v bf = *reinterpret_cast<const s8v*>(bbase + pos * 512 + ((g ^ (pos & 15)) << 4));
            acc[0] = __builtin_amdgcn_mfma_f32_16x16x32_bf16(af[0], bf, acc[0], 0, 0, 0);
            acc[1] = __builtin_amdgcn_mfma_f32_16x16x32_bf16(af[1], bf, acc[1], 0, 0, 0);
        }
    }

    int px = wq * 16 + q;
    if (px < 56) {
#pragma unroll
        for (int m = 0; m < 2; ++m)
#pragma unroll
            for (int r = 0; r < 4; ++r)
                t1[((size_t)(n * 32 + m * 16 + h * 4 + r) * 56 + y) * 56 + px] = acc[m][r];
    }
}

// ---------------- L3: merged mid kernel ----------------
// blocks [0,1792): t5+t8 MFMA -> t8T (XCD-swizzled);
// [1792,2240): t4 (XCD-swizzled);  [2240,2912): fuse_w1215b (LDS-staged w12).
__global__ __launch_bounds__(256) void k_mid(const float* __restrict__ t1,
                                             const float* __restrict__ p2w,
                                             const float* __restrict__ w5,
                                             const unsigned short* __restrict__ w8b,
                                             const float* __restrict__ w15,
                                             const float* __restrict__ w12,
                                             const float* __restrict__ W34,
                                             char* __restrict__ t8T,
                                             __hip_bfloat16* __restrict__ Wfb,
                                             float* __restrict__ t4) {
    __shared__ __align__(16) char lds[14336];
    const int t = threadIdx.x, b = blockIdx.x;

    if (b >= 2240) {  // ---- fuse_w1215b role ----
        int bb = b - 2240;
        int kk = bb >> 5;
        int oct = bb & 31;
        int dy = kk / 7, dx = kk - dy * 7;
        int ci = t & 31, col = t >> 5;
        int co = oct * 8 + col;
        float* w12s = (float*)lds;
        float s = 0.f;
        for (int c = 0; c < 16; ++c) {
            const float4* src = (const float4*)(w12 + c * 3584);
            for (int u = t; u < 896; u += 256)
                ((float4*)w12s)[u] = src[u];
            __syncthreads();
            int mbase = c * 16;
#pragma unroll
            for (int m = 0; m < 16; ++m) {
                float a = w15[co * 768 + (mbase + m) * 3 + dy];
                s += a * w12s[(m * 32 + ci) * 7 + dx];
            }
            __syncthreads();
        }
        Wfb[(size_t)kk * 8192 + co * 32 + ci] = __float2bfloat16(s);
        return;
    }
    if (b >= 1792) {  // ---- t4 role ----
        int by = b - 1792;
        int v4 = (by & 7) * 56 + (by >> 3);
        int n = v4 / 14;
        int y = (v4 % 14) * 4 + (t >> 6);
        int px = t & 63;
        if (px >= 56) return;
        float acc = 0.f;
#pragma unroll 4
        for (int ci = 0; ci < 32; ++ci) {
#pragma unroll
            for (int k1 = 0; k1 < 3; ++k1) {
                int yy = y + 2 * k1 - 2;
                if (yy < 0 || yy >= 56) continue;
                const float* r = t1 + ((size_t)(n * 32 + ci) * 56 + yy) * 56;
#pragma unroll
                for (int k2 = 0; k2 < 3; ++k2) {
                    int xx = px + 3 * k2 - 3;
                    if (xx >= 0 && xx < 56)
                        acc += r[xx] * W34[ci * 9 + k1 * 3 + k2];
                }
            }
        }
        t4[(size_t)(n * 56 + y) * 56 + px] = acc;
        return;
    }

    // ---- t5+t8 MFMA role ----
    const int v = (b & 7) * 224 + (b >> 3);
    const int n = v / 56, y = v % 56;
    const int w = t >> 6, l = t & 63, h = l >> 4, q = l & 15;
    const float* t1b = t1 + (size_t)(n * 32) * 3136;
    char* rowbuf = lds + 4864;

    if (t < 80) {
        int ph = t >> 2, g = t & 3;
        int pos = (ph < 6) ? ph : (56 + ph);
        *reinterpret_cast<s8v*>(lds + pos * 64 + ((g ^ ((pos >> 1) & 3)) << 4)) = (s8v)0;
    }
    if (t >= 80 && t < 136) {
        int u = t - 80;
        int ph = u >> 2, g = u & 3;
        int pos = (ph < 3) ? ph : (56 + ph);
        *reinterpret_cast<s8v*>(rowbuf + pos * 64 + ((g ^ ((pos >> 1) & 3)) << 4)) = (s8v)0;
    }
#pragma unroll
    for (int it = 0; it < 2; ++it) {
        int u = it * 256 + t;
        if (u < 448) {
            int ci = u / 14, xq = u % 14;
            float sc = p2w[ci];
            float4 s = {0.f, 0.f, 0.f, 0.f};
#pragma unroll
            for (int k = 0; k < 3; ++k) {
                int yy = y + 3 * k - 3;
                if (yy < 0 || yy >= 56) continue;
                float wv = w5[ci * 3 + k] * sc;
                float4 vv = *(const float4*)(t1b + (size_t)ci * 3136 + yy * 56 + xq * 4);
                s.x += wv * vv.x; s.y += wv * vv.y; s.z += wv * vv.z; s.w += wv * vv.w;
            }
            int g = ci >> 3, lo = (ci & 7) * 2;
#pragma unroll
            for (int j = 0; j < 4; ++j) {
                int pos = xq * 4 + j + 6;
                __hip_bfloat16 bv = __float2bfloat16(((const float*)&s)[j]);
                *(unsigned short*)(lds + pos * 64 + ((g ^ ((pos >> 1) & 3)) << 4) + lo) =
                    *(unsigned short*)&bv;
            }
        }
    }
    __syncthreads();

    f32x4 acc[2];
    acc[0] = (f32x4)0.f; acc[1] = (f32x4)0.f;
#pragma unroll
    for (int j = 0; j < 7; ++j) {
        s8v af[2];
#pragma unroll
        for (int m = 0; m < 2; ++m)
            af[m] = *reinterpret_cast<const s8v*>(
                w8b + (size_t)(((j * 4 + h) * 32 + m * 16 + q) * 8));
        int pos = w * 16 + q + 2 * j;
        s8v bf = *reinterpret_cast<const s8v*>(lds + pos * 64 + ((h ^ ((pos >> 1) & 3)) << 4));
        acc[0] = __builtin_amdgcn_mfma_f32_16x16x32_bf16(af[0], bf, acc[0], 0, 0, 0);
        acc[1] = __builtin_amdgcn_mfma_f32_16x16x32_bf16(af[1], bf, acc[1], 0, 0, 0);
    }

    int xx = w * 16 + q;
    if (xx < 56) {
        int pos = xx + 3;
#pragma unroll
        for (int m = 0; m < 2; ++m) {
#pragma unroll
            for (int r = 0; r < 4; ++r) {
                int co = m * 16 + h * 4 + r;
                __hip_bfloat16 bv = __float2bfloat16(acc[m][r]);
                *(unsigned short*)(rowbuf + pos * 64 + (((co >> 3) ^ ((pos >> 1) & 3)) << 4) +
                                   (co & 7) * 2) = *(unsigned short*)&bv;
            }
        }
    }
    __syncthreads();
    char* rowo = t8T + (size_t)(n * 56 + y) * 4480;
    for (int u = t; u < 280; u += 256)
        *reinterpret_cast<s8v*>(rowo + u * 16) = *reinterpret_cast<const s8v*>(rowbuf + u * 16);
}

// ---------------- L4: t8T -> t15 -> t16 + (pool->t11->t14 from t4) -> out ----------------
// grid 1792 (XCD-swizzled), block 512 = 8 waves, 1 row/block, wave = 32-co slice.
// Static fully-unrolled K-loop (zero-filled OOB dy rows). [best-known: 67 us]
__global__ __launch_bounds__(512) void k_t15r(const char* __restrict__ t8T,
                                              const unsigned short* __restrict__ Wfb,
                                              const float* __restrict__ w16,
                                              const float* __restrict__ w14,
                                              const float* __restrict__ t4,
                                              float* __restrict__ out) {
    __shared__ __align__(16) char lds[18816];
    float* Rr   = (float*)(lds + 13440);  // [5][64]
    float* Tt   = (float*)(lds + 14720);  // [3][64]
    float* t14l = (float*)(lds + 15488);  // [64]
    float* w16l = (float*)(lds + 15744);  // [768]
    const int t = threadIdx.x;
    const int b = blockIdx.x;
    const int vb = (b & 7) * 224 + (b >> 3);
    const int n = vb / 56, y = vb % 56;
    const int l = t & 63, h = l >> 4, q = l & 15;
    const int w = t >> 6;
    const int co0 = w * 32;
    const float* t4b = t4 + (size_t)n * 3136;

    for (int e = t; e < 840; e += 512) {
        int ridx = e / 280, u = e - ridx * 280;
        int yy = y + 2 * ridx - 2;
        s8v v = (s8v)0;
        if (yy >= 0 && yy < 56)
            v = *reinterpret_cast<const s8v*>(t8T + (size_t)(n * 56 + yy) * 4480 + u * 16);
        *reinterpret_cast<s8v*>(lds + ridx * 4480 + u * 16) = v;
    }
    for (int e = t; e < 768; e += 512) w16l[e] = w16[e];
    for (int e = t; e < 280; e += 512) {
        int ridx = e / 56, xx = e % 56;
        int yc = y - 2 + ridx;
        float rv = 0.f;
        if (yc >= 0 && yc < 56) {
            float mm = -3.4e38f;
#pragma unroll
            for (int i = 0; i < 7; ++i) {
                int yy = yc + 3 * i - 9;
                float v = (yy >= 0 && yy < 56) ? t4b[(size_t)yy * 56 + xx] : 0.f;
                mm = fmaxf(mm, v);
            }
            rv = fmaxf(mm, 0.f);
        }
        Rr[ridx * 64 + xx] = rv;
    }
    __syncthreads();
    for (int e = t; e < 168; e += 512) {
        int ti = e / 56, px = e % 56;
        int yt = y - 1 + ti;
        float s = 0.f;
        if (yt >= 0 && yt < 56) {
#pragma unroll
            for (int dy = 0; dy < 3; ++dy) {
                int yr = yt + dy - 1;
                if (yr < 0 || yr >= 56) continue;
                int row = ti + dy;
#pragma unroll
                for (int j = 0; j < 7; ++j) {
                    int xx = px + 3 * j - 9;
                    if (xx >= 0 && xx < 56) s += Rr[row * 64 + xx];
                }
            }
            s *= (1.f / 21.f);
        }
        Tt[ti * 64 + px] = s;
    }
    __syncthreads();
    if (t < 56) {
        int px = t;
        float s = 0.f;
#pragma unroll
        for (int dy = 0; dy < 3; ++dy) {
            int yy = y + dy - 1;
            if (yy < 0 || yy >= 56) continue;
#pragma unroll
            for (int dx = 0; dx < 3; ++dx) {
                int xx = px + dx - 1;
                if (xx < 0 || xx >= 56) continue;
                s += Tt[dy * 64 + xx] * w14[dy * 3 + dx];
            }
        }
        t14l[px] = s;
    }
    __syncthreads();

    f32x4 acc[2][4];
#pragma unroll
    for (int m = 0; m < 2; ++m)
#pragma unroll
        for (int nt = 0; nt < 4; ++nt)
            acc[m][nt] = (f32x4)0.f;

#pragma unroll
    for (int dy = 0; dy < 3; ++dy) {
        const char* bbase = lds + dy * 4480;
#pragma unroll
        for (int dx = 0; dx < 7; ++dx) {
            const int kk = dy * 7 + dx;
            s8v af[2];
#pragma unroll
            for (int m = 0; m < 2; ++m)
                af[m] = *reinterpret_cast<const s8v*>(
                    Wfb + (size_t)kk * 8192 + (co0 + m * 16 + q) * 32 + h * 8);
            s8v bf[4];
#pragma unroll
            for (int nt = 0; nt < 4; ++nt) {
                int xp = nt * 16 + q + dx;
                bf[nt] = *reinterpret_cast<const s8v*>(
                    bbase + xp * 64 + ((h ^ ((xp >> 1) & 3)) << 4));
            }
#pragma unroll
            for (int nt = 0; nt < 4; ++nt)
#pragma unroll
                for (int m = 0; m < 2; ++m)
                    acc[m][nt] =
                        __builtin_amdgcn_mfma_f32_16x16x32_bf16(af[m], bf[nt], acc[m][nt], 0, 0, 0);
        }
    }

    float t14v[4];
#pragma unroll
    for (int nt = 0; nt < 4; ++nt) {
        int xx = nt * 16 + q;
        t14v[nt] = (xx < 56) ? t14l[xx] : 0.f;
    }
    const int srcm = (l & 48) | ((q + 13) & 15);
    const int srcp = (l & 48) | ((q + 3) & 15);
#pragma unroll
    for (int m = 0; m < 2; ++m) {
#pragma unroll
        for (int r = 0; r < 4; ++r) {
            int co = co0 + m * 16 + h * 4 + r;
            float wa = w16l[co * 3], wb = w16l[co * 3 + 1], wc = w16l[co * 3 + 2];
            float v[4], rm[4], rp[4];
#pragma unroll
            for (int nt = 0; nt < 4; ++nt) v[nt] = acc[m][nt][r];
#pragma unroll
            for (int nt = 0; nt < 4; ++nt) {
                rm[nt] = __shfl(v[nt], srcm, 64);
                rp[nt] = __shfl(v[nt], srcp, 64);
            }
            float* orow = out + ((size_t)(n * 256 + co) * 56 + y) * 56;
#pragma unroll
            for (int nt = 0; nt < 4; ++nt) {
                int xx = nt * 16 + q;
                float vm = (q >= 3) ? rm[nt] : (nt > 0 ? rm[nt - 1] : 0.f);
                float vp = (q < 13) ? rp[nt] : (nt < 3 ? rp[nt + 1] : 0.f);
                float s = v[nt] * wb + t14v[nt];
                s += (xx >= 3) ? vm * wa : 0.f;
                s += (xx <= 52) ? vp * wc : 0.f;
                if (xx < 56) orow[xx] = s;
            }
        }
    }
}

extern "C" void kernel_launch(void* const* d_in, const int* in_sizes, int n_in,
                              void* d_out, int out_size, void* d_ws, size_t ws_size,
                              hipStream_t stream) {
    const float* x   = (const float*)d_in[0];
    const float* w1  = (const float*)d_in[1];
    const float* p2w = (const float*)d_in[2];
    const float* w3  = (const float*)d_in[3];
    const float* w4  = (const float*)d_in[4];
    const float* w5  = (const float*)d_in[5];
    const float* w8  = (const float*)d_in[6];
    const float* w12 = (const float*)d_in[7];
    const float* w14 = (const float*)d_in[8];
    const float* w15 = (const float*)d_in[9];
    const float* w16 = (const float*)d_in[10];
    float* out = (float*)d_out;

    float* ws = (float*)d_ws;
    float* t1   = ws;                      // 3211264 f32
    char*  t8T  = (char*)(t1 + 3211264);   // 8,028,160 B
    float* t4   = t1 + 2 * 3211264;        // 100352 f32
    float* W34  = t4 + 100352;             // 288 f32
    __hip_bfloat16* Wfb = (__hip_bfloat16*)(W34 + 288);   // 172032 bf16
    __hip_bfloat16* w1b = Wfb + 172032;                   // 24576 bf16
    __hip_bfloat16* w8b = w1b + 24576;                    // 7168 bf16

    fuse_small<<<128, 256, 0, stream>>>(w3, w4, w1, w8, W34, w1b, w8b);
    k_t1f2<<<896, 512, 0, stream>>>(x, (const unsigned short*)w1b, t1);
    k_mid<<<2912, 256, 0, stream>>>(t1, p2w, w5, (const unsigned short*)w8b,
                                    w15, w12, W34, t8T, Wfb, t4);
    k_t15r<<<1792, 512, 0, stream>>>(t8T, (const unsigned short*)Wfb, w16, w14, t4, out);
}

// Round 19
// 146.894 us; speedup vs baseline: 1.1389x; 1.0178x over previous
//
#include <hip/hip_runtime.h>
#include <hip/hip_bf16.h>
#include <cstddef>

typedef __attribute__((ext_vector_type(8))) short s8v;
typedef __attribute__((ext_vector_type(4))) float f32x4;

// ---------------- L1: merged small repacks: W34 (288), w1b (24576), w8b (7168) ----------------
__global__ void fuse_small(const float* __restrict__ w3, const float* __restrict__ w4,
                           const float* __restrict__ w1, const float* __restrict__ w8,
                           float* __restrict__ W34, __hip_bfloat16* __restrict__ w1b,
                           __hip_bfloat16* __restrict__ w8b) {
    int idx = blockIdx.x * blockDim.x + threadIdx.x;
    if (idx < 288) {
        int ci = idx / 9, k1 = (idx / 3) % 3, k2 = idx % 3;
        float s = 0.f;
        for (int co = 0; co < 256; ++co)
            s += w3[(co * 32 + ci) * 3 + k1] * w4[co * 3 + k2];
        W34[idx] = s;
    }
    int i1 = idx - 512;
    if (i1 >= 0 && i1 < 24576) {
        int j = i1 & 7, co = (i1 >> 3) & 31, h = (i1 >> 8) & 3, c = (i1 >> 10) & 7, k = i1 >> 13;
        int ci = c * 32 + h * 8 + j;
        w1b[i1] = __float2bfloat16(w1[(co * 256 + ci) * 3 + k]);
    }
    int i2 = idx - 25600;
    if (i2 >= 0 && i2 < 7168) {
        int jj = i2 & 7, co = (i2 >> 3) & 31, h = (i2 >> 8) & 3, j = i2 >> 10;
        w8b[i2] = __float2bfloat16(w8[co * 224 + (h * 8 + jj) * 7 + j]);
    }
}

// ---------------- L2: t1 fused MFMA, y-pair blocks for 448B DRAM bursts ----------------
__global__ __launch_bounds__(512) void k_t1f2(const float* __restrict__ x,
                                              const unsigned short* __restrict__ w1b,
                                              float* __restrict__ t1) {
    __shared__ __align__(16) char lds[71680];   // 2 x 35840
    const int t = threadIdx.x, b = blockIdx.x;
    const int vb = (b & 7) * 112 + (b >> 3);    // XCD-bijective (896 = 8 x 112)
    const int n = vb / 28, y0 = (vb % 28) * 2;
    const int w = t >> 6, l = t & 63, h = l >> 4, q = l & 15;
    const int rg = w >> 2, wq = w & 3;
    const int y = y0 + rg;
    const float* xr = x + (size_t)(n * 256) * 3136 + y0 * 56;

#pragma unroll
    for (int it = 0; it < 2; ++it) {
        int e = it * 512 + t;
        if (e < 896) {
            int rt = e / 448, u = e % 448;
            int pi = u >> 5, g = u & 31;
            int pos = (pi < 3) ? pi : (56 + pi);
            *reinterpret_cast<s8v*>(lds + rt * 35840 + pos * 512 + ((g ^ (pos & 15)) << 4)) =
                (s8v)0;
        }
    }
    float4 va[7], vb7[7];
#pragma unroll
    for (int it = 0; it < 7; ++it) {
        int u = it * 512 + t;
        int c2 = u / 28, xq2 = u % 28;
        int ci = c2 * 2;
        va[it]  = *(const float4*)(xr + (size_t)ci * 3136 + xq2 * 4);
        vb7[it] = *(const float4*)(xr + (size_t)(ci + 1) * 3136 + xq2 * 4);
    }
#pragma unroll
    for (int it = 0; it < 7; ++it) {
        int u = it * 512 + t;
        int c2 = u / 28, xq2 = u % 28;
        int ci = c2 * 2;
        int rt = (xq2 >= 14) ? 1 : 0;
        int xq = xq2 - rt * 14;
        int g = ci >> 3, lo = (ci & 7) * 2;
        char* base = lds + rt * 35840;
#pragma unroll
        for (int j = 0; j < 4; ++j) {
            int pos = xq * 4 + j + 3;
            __hip_bfloat16 b0 = __float2bfloat16(((const float*)&va[it])[j]);
            __hip_bfloat16 b1 = __float2bfloat16(((const float*)&vb7[it])[j]);
            unsigned int wd = (unsigned int)(*(unsigned short*)&b0) |
                              ((unsigned int)(*(unsigned short*)&b1) << 16);
            *(unsigned int*)(base + pos * 512 + ((g ^ (pos & 15)) << 4) + lo) = wd;
        }
    }
    __syncthreads();

    f32x4 acc[2];
    acc[0] = (f32x4)0.f;
    acc[1] = (f32x4)0.f;
    const char* bbase = lds + rg * 35840;

#pragma unroll 4
    for (int c = 0; c < 8; ++c) {
        const int g = c * 4 + h;
#pragma unroll
        for (int k = 0; k < 3; ++k) {
            s8v af[2];
#pragma unroll
            for (int m = 0; m < 2; ++m)
                af[m] = *reinterpret_cast<const s8v*>(
                    w1b + (size_t)((((k * 8 + c) * 4 + h) * 32 + m * 16 + q) * 8));
            int pos = wq * 16 + q + 3 * k;
            s8v bf = *reinterpret_cast<const s8v*>(bbase + pos * 512 + ((g ^ (pos & 15)) << 4));
            acc[0] = __builtin_amdgcn_mfma_f32_16x16x32_bf16(af[0], bf, acc[0], 0, 0, 0);
            acc[1] = __builtin_amdgcn_mfma_f32_16x16x32_bf16(af[1], bf, acc[1], 0, 0, 0);
        }
    }

    int px = wq * 16 + q;
    if (px < 56) {
#pragma unroll
        for (int m = 0; m < 2; ++m)
#pragma unroll
            for (int r = 0; r < 4; ++r)
                t1[((size_t)(n * 32 + m * 16 + h * 4 + r) * 56 + y) * 56 + px] = acc[m][r];
    }
}

// ---------------- L3: merged mid kernel ----------------
// blocks [0,896): t5+t8 MFMA y-pair -> t8T (XCD-swizzled, 448B t1 bursts);
// [896,1344): t4 (XCD-swizzled);  [1344,2016): fuse_w1215b (LDS-staged w12).
__global__ __launch_bounds__(256) void k_mid(const float* __restrict__ t1,
                                             const float* __restrict__ p2w,
                                             const float* __restrict__ w5,
                                             const unsigned short* __restrict__ w8b,
                                             const float* __restrict__ w15,
                                             const float* __restrict__ w12,
                                             const float* __restrict__ W34,
                                             char* __restrict__ t8T,
                                             __hip_bfloat16* __restrict__ Wfb,
                                             float* __restrict__ t4) {
    __shared__ __align__(16) char lds[18688];
    const int t = threadIdx.x, b = blockIdx.x;

    if (b >= 1344) {  // ---- fuse_w1215b role ----
        int bb = b - 1344;
        int kk = bb >> 5;
        int oct = bb & 31;
        int dy = kk / 7, dx = kk - dy * 7;
        int ci = t & 31, col = t >> 5;
        int co = oct * 8 + col;
        float* w12s = (float*)lds;
        float s = 0.f;
        for (int c = 0; c < 16; ++c) {
            const float4* src = (const float4*)(w12 + c * 3584);
            for (int u = t; u < 896; u += 256)
                ((float4*)w12s)[u] = src[u];
            __syncthreads();
            int mbase = c * 16;
#pragma unroll
            for (int m = 0; m < 16; ++m) {
                float a = w15[co * 768 + (mbase + m) * 3 + dy];
                s += a * w12s[(m * 32 + ci) * 7 + dx];
            }
            __syncthreads();
        }
        Wfb[(size_t)kk * 8192 + co * 32 + ci] = __float2bfloat16(s);
        return;
    }
    if (b >= 896) {  // ---- t4 role (XCD-swizzled: 448 = 8 x 56) ----
        int by = b - 896;
        int v4 = (by & 7) * 56 + (by >> 3);
        int n = v4 / 14;
        int y = (v4 % 14) * 4 + (t >> 6);
        int px = t & 63;
        if (px >= 56) return;
        float acc = 0.f;
#pragma unroll 4
        for (int ci = 0; ci < 32; ++ci) {
#pragma unroll
            for (int k1 = 0; k1 < 3; ++k1) {
                int yy = y + 2 * k1 - 2;
                if (yy < 0 || yy >= 56) continue;
                const float* r = t1 + ((size_t)(n * 32 + ci) * 56 + yy) * 56;
#pragma unroll
                for (int k2 = 0; k2 < 3; ++k2) {
                    int xx = px + 3 * k2 - 3;
                    if (xx >= 0 && xx < 56)
                        acc += r[xx] * W34[ci * 9 + k1 * 3 + k2];
                }
            }
        }
        t4[(size_t)(n * 56 + y) * 56 + px] = acc;
        return;
    }

    // ---- t5+t8 MFMA role, y-pair (XCD-swizzled: 896 = 8 x 112) ----
    // LDS: stage[2] @ 0,4864 ([76 pos][32ci] bf16, slot g^((pos>>1)&3));
    //      rowbuf[2] @ 9728,14208.
    const int vb = (b & 7) * 112 + (b >> 3);
    const int n = vb / 28, y0 = (vb % 28) * 2;
    const int w = t >> 6, l = t & 63, h = l >> 4, q = l & 15;
    const int rg = w >> 1, half = w & 1;
    const float* t1b = t1 + (size_t)(n * 32) * 3136;
    char* rb0 = lds + 9728;

    // stage halo zeros: 2 tiles x pos {0..5,62..75} x 4 g = 160 units
    for (int e = t; e < 160; e += 256) {
        int rt = e / 80, u = e % 80;
        int ph = u >> 2, g = u & 3;
        int pos = (ph < 6) ? ph : (56 + ph);
        *reinterpret_cast<s8v*>(lds + rt * 4864 + pos * 64 + ((g ^ ((pos >> 1) & 3)) << 4)) =
            (s8v)0;
    }
    // rowbuf halo zeros: 2 bufs x pos {0,1,2,59..69} x 4 g = 112 units
    for (int e = t; e < 112; e += 256) {
        int rt = e / 56, u = e % 56;
        int ph = u >> 2, g = u & 3;
        int pos = (ph < 3) ? ph : (56 + ph);
        *reinterpret_cast<s8v*>(rb0 + rt * 4480 + pos * 64 + ((g ^ ((pos >> 1) & 3)) << 4)) =
            (s8v)0;
    }
    // stage: 896 units (ci, xq2); 448B contiguous t1 reads cover both rows
    for (int e = t; e < 896; e += 256) {
        int ci = e / 28, xq2 = e % 28;
        int rt = (xq2 >= 14) ? 1 : 0;
        int xq = xq2 - rt * 14;
        float sc = p2w[ci];
        float4 s = {0.f, 0.f, 0.f, 0.f};
#pragma unroll
        for (int k = 0; k < 3; ++k) {
            int yy = y0 - 3 + 3 * k + rt;
            if (yy < 0 || yy >= 56) continue;
            float wv = w5[ci * 3 + k] * sc;
            float4 vv = *(const float4*)(t1b + (size_t)ci * 3136 + (y0 - 3 + 3 * k) * 56 + xq2 * 4);
            s.x += wv * vv.x; s.y += wv * vv.y; s.z += wv * vv.z; s.w += wv * vv.w;
        }
        int g = ci >> 3, lo = (ci & 7) * 2;
        char* base = lds + rt * 4864;
#pragma unroll
        for (int j = 0; j < 4; ++j) {
            int pos = xq * 4 + j + 6;
            __hip_bfloat16 bv = __float2bfloat16(((const float*)&s)[j]);
            *(unsigned short*)(base + pos * 64 + ((g ^ ((pos >> 1) & 3)) << 4) + lo) =
                *(unsigned short*)&bv;
        }
    }
    __syncthreads();

    // MFMA: wave (rg,half): row y0+rg, px quarters {half*2, half*2+1}
    const char* sb = lds + rg * 4864;
    f32x4 acc[2][2];  // [nt][m]
    acc[0][0] = (f32x4)0.f; acc[0][1] = (f32x4)0.f;
    acc[1][0] = (f32x4)0.f; acc[1][1] = (f32x4)0.f;
#pragma unroll
    for (int j = 0; j < 7; ++j) {
        s8v af[2];
#pragma unroll
        for (int m = 0; m < 2; ++m)
            af[m] = *reinterpret_cast<const s8v*>(
                w8b + (size_t)(((j * 4 + h) * 32 + m * 16 + q) * 8));
#pragma unroll
        for (int nt = 0; nt < 2; ++nt) {
            int pos = (half * 2 + nt) * 16 + q + 2 * j;
            s8v bf = *reinterpret_cast<const s8v*>(sb + pos * 64 + ((h ^ ((pos >> 1) & 3)) << 4));
            acc[nt][0] = __builtin_amdgcn_mfma_f32_16x16x32_bf16(af[0], bf, acc[nt][0], 0, 0, 0);
            acc[nt][1] = __builtin_amdgcn_mfma_f32_16x16x32_bf16(af[1], bf, acc[nt][1], 0, 0, 0);
        }
    }

    // scatter to rowbuf[rg]
    char* rb = rb0 + rg * 4480;
#pragma unroll
    for (int nt = 0; nt < 2; ++nt) {
        int xx = (half * 2 + nt) * 16 + q;
        if (xx < 56) {
            int pos = xx + 3;
#pragma unroll
            for (int m = 0; m < 2; ++m)
#pragma unroll
                for (int r = 0; r < 4; ++r) {
                    int co = m * 16 + h * 4 + r;
                    __hip_bfloat16 bv = __float2bfloat16(acc[nt][m][r]);
                    *(unsigned short*)(rb + pos * 64 + (((co >> 3) ^ ((pos >> 1) & 3)) << 4) +
                                       (co & 7) * 2) = *(unsigned short*)&bv;
                }
        }
    }
    __syncthreads();
    // coalesced copy: 2 rows x 280 x 16B
    for (int e = t; e < 560; e += 256) {
        int ridx = e / 280, u = e - ridx * 280;
        char* rowo = t8T + (size_t)(n * 56 + y0 + ridx) * 4480;
        *reinterpret_cast<s8v*>(rowo + u * 16) =
            *reinterpret_cast<const s8v*>(rb0 + ridx * 4480 + u * 16);
    }
}

// ---------------- L4: t8T -> t15 -> t16 + (pool->t11->t14 from t4) -> out ----------------
// grid 1792 (XCD-swizzled), block 512 = 8 waves, 1 row/block, wave = 32-co slice.
// Static fully-unrolled K-loop (zero-filled OOB dy rows). [best-known: 67 us]
__global__ __launch_bounds__(512) void k_t15r(const char* __restrict__ t8T,
                                              const unsigned short* __restrict__ Wfb,
                                              const float* __restrict__ w16,
                                              const float* __restrict__ w14,
                                              const float* __restrict__ t4,
                                              float* __restrict__ out) {
    __shared__ __align__(16) char lds[18816];
    float* Rr   = (float*)(lds + 13440);
    float* Tt   = (float*)(lds + 14720);
    float* t14l = (float*)(lds + 15488);
    float* w16l = (float*)(lds + 15744);
    const int t = threadIdx.x;
    const int b = blockIdx.x;
    const int vb = (b & 7) * 224 + (b >> 3);
    const int n = vb / 56, y = vb % 56;
    const int l = t & 63, h = l >> 4, q = l & 15;
    const int w = t >> 6;
    const int co0 = w * 32;
    const float* t4b = t4 + (size_t)n * 3136;

    for (int e = t; e < 840; e += 512) {
        int ridx = e / 280, u = e - ridx * 280;
        int yy = y + 2 * ridx - 2;
        s8v v = (s8v)0;
        if (yy >= 0 && yy < 56)
            v = *reinterpret_cast<const s8v*>(t8T + (size_t)(n * 56 + yy) * 4480 + u * 16);
        *reinterpret_cast<s8v*>(lds + ridx * 4480 + u * 16) = v;
    }
    for (int e = t; e < 768; e += 512) w16l[e] = w16[e];
    for (int e = t; e < 280; e += 512) {
        int ridx = e / 56, xx = e % 56;
        int yc = y - 2 + ridx;
        float rv = 0.f;
        if (yc >= 0 && yc < 56) {
            float mm = -3.4e38f;
#pragma unroll
            for (int i = 0; i < 7; ++i) {
                int yy = yc + 3 * i - 9;
                float v = (yy >= 0 && yy < 56) ? t4b[(size_t)yy * 56 + xx] : 0.f;
                mm = fmaxf(mm, v);
            }
            rv = fmaxf(mm, 0.f);
        }
        Rr[ridx * 64 + xx] = rv;
    }
    __syncthreads();
    for (int e = t; e < 168; e += 512) {
        int ti = e / 56, px = e % 56;
        int yt = y - 1 + ti;
        float s = 0.f;
        if (yt >= 0 && yt < 56) {
#pragma unroll
            for (int dy = 0; dy < 3; ++dy) {
                int yr = yt + dy - 1;
                if (yr < 0 || yr >= 56) continue;
                int row = ti + dy;
#pragma unroll
                for (int j = 0; j < 7; ++j) {
                    int xx = px + 3 * j - 9;
                    if (xx >= 0 && xx < 56) s += Rr[row * 64 + xx];
                }
            }
            s *= (1.f / 21.f);
        }
        Tt[ti * 64 + px] = s;
    }
    __syncthreads();
    if (t < 56) {
        int px = t;
        float s = 0.f;
#pragma unroll
        for (int dy = 0; dy < 3; ++dy) {
            int yy = y + dy - 1;
            if (yy < 0 || yy >= 56) continue;
#pragma unroll
            for (int dx = 0; dx < 3; ++dx) {
                int xx = px + dx - 1;
                if (xx < 0 || xx >= 56) continue;
                s += Tt[dy * 64 + xx] * w14[dy * 3 + dx];
            }
        }
        t14l[px] = s;
    }
    __syncthreads();

    f32x4 acc[2][4];
#pragma unroll
    for (int m = 0; m < 2; ++m)
#pragma unroll
        for (int nt = 0; nt < 4; ++nt)
            acc[m][nt] = (f32x4)0.f;

#pragma unroll
    for (int dy = 0; dy < 3; ++dy) {
        const char* bbase = lds + dy * 4480;
#pragma unroll
        for (int dx = 0; dx < 7; ++dx) {
            const int kk = dy * 7 + dx;
            s8v af[2];
#pragma unroll
            for (int m = 0; m < 2; ++m)
                af[m] = *reinterpret_cast<const s8v*>(
                    Wfb + (size_t)kk * 8192 + (co0 + m * 16 + q) * 32 + h * 8);
            s8v bf[4];
#pragma unroll
            for (int nt = 0; nt < 4; ++nt) {
                int xp = nt * 16 + q + dx;
                bf[nt] = *reinterpret_cast<const s8v*>(
                    bbase + xp * 64 + ((h ^ ((xp >> 1) & 3)) << 4));
            }
#pragma unroll
            for (int nt = 0; nt < 4; ++nt)
#pragma unroll
                for (int m = 0; m < 2; ++m)
                    acc[m][nt] =
                        __builtin_amdgcn_mfma_f32_16x16x32_bf16(af[m], bf[nt], acc[m][nt], 0, 0, 0);
        }
    }

    float t14v[4];
#pragma unroll
    for (int nt = 0; nt < 4; ++nt) {
        int xx = nt * 16 + q;
        t14v[nt] = (xx < 56) ? t14l[xx] : 0.f;
    }
    const int srcm = (l & 48) | ((q + 13) & 15);
    const int srcp = (l & 48) | ((q + 3) & 15);
#pragma unroll
    for (int m = 0; m < 2; ++m) {
#pragma unroll
        for (int r = 0; r < 4; ++r) {
            int co = co0 + m * 16 + h * 4 + r;
            float wa = w16l[co * 3], wb = w16l[co * 3 + 1], wc = w16l[co * 3 + 2];
            float v[4], rm[4], rp[4];
#pragma unroll
            for (int nt = 0; nt < 4; ++nt) v[nt] = acc[m][nt][r];
#pragma unroll
            for (int nt = 0; nt < 4; ++nt) {
                rm[nt] = __shfl(v[nt], srcm, 64);
                rp[nt] = __shfl(v[nt], srcp, 64);
            }
            float* orow = out + ((size_t)(n * 256 + co) * 56 + y) * 56;
#pragma unroll
            for (int nt = 0; nt < 4; ++nt) {
                int xx = nt * 16 + q;
                float vm = (q >= 3) ? rm[nt] : (nt > 0 ? rm[nt - 1] : 0.f);
                float vp = (q < 13) ? rp[nt] : (nt < 3 ? rp[nt + 1] : 0.f);
                float s = v[nt] * wb + t14v[nt];
                s += (xx >= 3) ? vm * wa : 0.f;
                s += (xx <= 52) ? vp * wc : 0.f;
                if (xx < 56) orow[xx] = s;
            }
        }
    }
}

extern "C" void kernel_launch(void* const* d_in, const int* in_sizes, int n_in,
                              void* d_out, int out_size, void* d_ws, size_t ws_size,
                              hipStream_t stream) {
    const float* x   = (const float*)d_in[0];
    const float* w1  = (const float*)d_in[1];
    const float* p2w = (const float*)d_in[2];
    const float* w3  = (const float*)d_in[3];
    const float* w4  = (const float*)d_in[4];
    const float* w5  = (const float*)d_in[5];
    const float* w8  = (const float*)d_in[6];
    const float* w12 = (const float*)d_in[7];
    const float* w14 = (const float*)d_in[8];
    const float* w15 = (const float*)d_in[9];
    const float* w16 = (const float*)d_in[10];
    float* out = (float*)d_out;

    float* ws = (float*)d_ws;
    float* t1   = ws;                      // 3211264 f32
    char*  t8T  = (char*)(t1 + 3211264);   // 8,028,160 B
    float* t4   = t1 + 2 * 3211264;        // 100352 f32
    float* W34  = t4 + 100352;             // 288 f32
    __hip_bfloat16* Wfb = (__hip_bfloat16*)(W34 + 288);   // 172032 bf16
    __hip_bfloat16* w1b = Wfb + 172032;                   // 24576 bf16
    __hip_bfloat16* w8b = w1b + 24576;                    // 7168 bf16

    fuse_small<<<128, 256, 0, stream>>>(w3, w4, w1, w8, W34, w1b, w8b);
    k_t1f2<<<896, 512, 0, stream>>>(x, (const unsigned short*)w1b, t1);
    k_mid<<<2016, 256, 0, stream>>>(t1, p2w, w5, (const unsigned short*)w8b,
                                    w15, w12, W34, t8T, Wfb, t4);
    k_t15r<<<1792, 512, 0, stream>>>(t8T, (const unsigned short*)Wfb, w16, w14, t4, out);
}

// Round 20
// 143.299 us; speedup vs baseline: 1.1675x; 1.0251x over previous
//
#include <hip/hip_runtime.h>
#include <hip/hip_bf16.h>
#include <cstddef>

typedef __attribute__((ext_vector_type(8))) short s8v;
typedef __attribute__((ext_vector_type(4))) float f32x4;

// ---------------- L1: w1b repack only (needed by L2) ----------------
__global__ void fuse_w1b(const float* __restrict__ w1, __hip_bfloat16* __restrict__ w1b) {
    int idx = blockIdx.x * blockDim.x + threadIdx.x;
    if (idx >= 24576) return;
    int j = idx & 7, co = (idx >> 3) & 31, h = (idx >> 8) & 3, c = (idx >> 10) & 7, k = idx >> 13;
    int ci = c * 32 + h * 8 + j;
    w1b[idx] = __float2bfloat16(w1[(co * 256 + ci) * 3 + k]);
}

// ---------------- L2: t1 fused MFMA (y-pair, 448B bursts) + concurrent W34/w8b repacks ----------------
// blocks [0,896): t1 conv; blocks [896,1024): W34 (288) + w8b (7168) repacks
// (consumed only by L3 -> run in t1's HBM latency shadow).
__global__ __launch_bounds__(512) void k_t1f2(const float* __restrict__ x,
                                              const unsigned short* __restrict__ w1b,
                                              const float* __restrict__ w3,
                                              const float* __restrict__ w4,
                                              const float* __restrict__ w8,
                                              float* __restrict__ t1,
                                              float* __restrict__ W34,
                                              __hip_bfloat16* __restrict__ w8b) {
    __shared__ __align__(16) char lds[71680];   // 2 x 35840
    const int t = threadIdx.x, b = blockIdx.x;

    if (b >= 896) {  // ---- small-repack role ----
        int idx = (b - 896) * 512 + t;
        if (idx < 288) {
            int ci = idx / 9, k1 = (idx / 3) % 3, k2 = idx % 3;
            float s = 0.f;
            for (int co = 0; co < 256; ++co)
                s += w3[(co * 32 + ci) * 3 + k1] * w4[co * 3 + k2];
            W34[idx] = s;
        }
        int i2 = idx - 512;
        if (i2 >= 0 && i2 < 7168) {
            int jj = i2 & 7, co = (i2 >> 3) & 31, h = (i2 >> 8) & 3, j = i2 >> 10;
            w8b[i2] = __float2bfloat16(w8[co * 224 + (h * 8 + jj) * 7 + j]);
        }
        return;
    }

    const int vb = (b & 7) * 112 + (b >> 3);    // XCD-bijective (896 = 8 x 112)
    const int n = vb / 28, y0 = (vb % 28) * 2;
    const int w = t >> 6, l = t & 63, h = l >> 4, q = l & 15;
    const int rg = w >> 2, wq = w & 3;
    const int y = y0 + rg;
    const float* xr = x + (size_t)(n * 256) * 3136 + y0 * 56;

#pragma unroll
    for (int it = 0; it < 2; ++it) {
        int e = it * 512 + t;
        if (e < 896) {
            int rt = e / 448, u = e % 448;
            int pi = u >> 5, g = u & 31;
            int pos = (pi < 3) ? pi : (56 + pi);
            *reinterpret_cast<s8v*>(lds + rt * 35840 + pos * 512 + ((g ^ (pos & 15)) << 4)) =
                (s8v)0;
        }
    }
    float4 va[7], vb7[7];
#pragma unroll
    for (int it = 0; it < 7; ++it) {
        int u = it * 512 + t;
        int c2 = u / 28, xq2 = u % 28;
        int ci = c2 * 2;
        va[it]  = *(const float4*)(xr + (size_t)ci * 3136 + xq2 * 4);
        vb7[it] = *(const float4*)(xr + (size_t)(ci + 1) * 3136 + xq2 * 4);
    }
#pragma unroll
    for (int it = 0; it < 7; ++it) {
        int u = it * 512 + t;
        int c2 = u / 28, xq2 = u % 28;
        int ci = c2 * 2;
        int rt = (xq2 >= 14) ? 1 : 0;
        int xq = xq2 - rt * 14;
        int g = ci >> 3, lo = (ci & 7) * 2;
        char* base = lds + rt * 35840;
#pragma unroll
        for (int j = 0; j < 4; ++j) {
            int pos = xq * 4 + j + 3;
            __hip_bfloat16 b0 = __float2bfloat16(((const float*)&va[it])[j]);
            __hip_bfloat16 b1 = __float2bfloat16(((const float*)&vb7[it])[j]);
            unsigned int wd = (unsigned int)(*(unsigned short*)&b0) |
                              ((unsigned int)(*(unsigned short*)&b1) << 16);
            *(unsigned int*)(base + pos * 512 + ((g ^ (pos & 15)) << 4) + lo) = wd;
        }
    }
    __syncthreads();

    f32x4 acc[2];
    acc[0] = (f32x4)0.f;
    acc[1] = (f32x4)0.f;
    const char* bbase = lds + rg * 35840;

#pragma unroll 4
    for (int c = 0; c < 8; ++c) {
        const int g = c * 4 + h;
#pragma unroll
        for (int k = 0; k < 3; ++k) {
            s8v af[2];
#pragma unroll
            for (int m = 0; m < 2; ++m)
                af[m] = *reinterpret_cast<const s8v*>(
                    w1b + (size_t)((((k * 8 + c) * 4 + h) * 32 + m * 16 + q) * 8));
            int pos = wq * 16 + q + 3 * k;
            s8v bf = *reinterpret_cast<const s8v*>(bbase + pos * 512 + ((g ^ (pos & 15)) << 4));
            acc[0] = __builtin_amdgcn_mfma_f32_16x16x32_bf16(af[0], bf, acc[0], 0, 0, 0);
            acc[1] = __builtin_amdgcn_mfma_f32_16x16x32_bf16(af[1], bf, acc[1], 0, 0, 0);
        }
    }

    int px = wq * 16 + q;
    if (px < 56) {
#pragma unroll
        for (int m = 0; m < 2; ++m)
#pragma unroll
            for (int r = 0; r < 4; ++r)
                t1[((size_t)(n * 32 + m * 16 + h * 4 + r) * 56 + y) * 56 + px] = acc[m][r];
    }
}

// ---------------- L3: merged mid kernel ----------------
// blocks [0,896): t5+t8 MFMA y-pair -> t8T (XCD-swizzled, 448B t1 bursts);
// [896,1344): t4 (XCD-swizzled);  [1344,2016): fuse_w1215b (LDS-staged w12).
__global__ __launch_bounds__(256) void k_mid(const float* __restrict__ t1,
                                             const float* __restrict__ p2w,
                                             const float* __restrict__ w5,
                                             const unsigned short* __restrict__ w8b,
                                             const float* __restrict__ w15,
                                             const float* __restrict__ w12,
                                             const float* __restrict__ W34,
                                             char* __restrict__ t8T,
                                             __hip_bfloat16* __restrict__ Wfb,
                                             float* __restrict__ t4) {
    __shared__ __align__(16) char lds[18688];
    const int t = threadIdx.x, b = blockIdx.x;

    if (b >= 1344) {  // ---- fuse_w1215b role ----
        int bb = b - 1344;
        int kk = bb >> 5;
        int oct = bb & 31;
        int dy = kk / 7, dx = kk - dy * 7;
        int ci = t & 31, col = t >> 5;
        int co = oct * 8 + col;
        float* w12s = (float*)lds;
        float s = 0.f;
        for (int c = 0; c < 16; ++c) {
            const float4* src = (const float4*)(w12 + c * 3584);
            for (int u = t; u < 896; u += 256)
                ((float4*)w12s)[u] = src[u];
            __syncthreads();
            int mbase = c * 16;
#pragma unroll
            for (int m = 0; m < 16; ++m) {
                float a = w15[co * 768 + (mbase + m) * 3 + dy];
                s += a * w12s[(m * 32 + ci) * 7 + dx];
            }
            __syncthreads();
        }
        Wfb[(size_t)kk * 8192 + co * 32 + ci] = __float2bfloat16(s);
        return;
    }
    if (b >= 896) {  // ---- t4 role (XCD-swizzled: 448 = 8 x 56) ----
        int by = b - 896;
        int v4 = (by & 7) * 56 + (by >> 3);
        int n = v4 / 14;
        int y = (v4 % 14) * 4 + (t >> 6);
        int px = t & 63;
        if (px >= 56) return;
        float acc = 0.f;
#pragma unroll 4
        for (int ci = 0; ci < 32; ++ci) {
#pragma unroll
            for (int k1 = 0; k1 < 3; ++k1) {
                int yy = y + 2 * k1 - 2;
                if (yy < 0 || yy >= 56) continue;
                const float* r = t1 + ((size_t)(n * 32 + ci) * 56 + yy) * 56;
#pragma unroll
                for (int k2 = 0; k2 < 3; ++k2) {
                    int xx = px + 3 * k2 - 3;
                    if (xx >= 0 && xx < 56)
                        acc += r[xx] * W34[ci * 9 + k1 * 3 + k2];
                }
            }
        }
        t4[(size_t)(n * 56 + y) * 56 + px] = acc;
        return;
    }

    // ---- t5+t8 MFMA role, y-pair (XCD-swizzled: 896 = 8 x 112) ----
    const int vb = (b & 7) * 112 + (b >> 3);
    const int n = vb / 28, y0 = (vb % 28) * 2;
    const int w = t >> 6, l = t & 63, h = l >> 4, q = l & 15;
    const int rg = w >> 1, half = w & 1;
    const float* t1b = t1 + (size_t)(n * 32) * 3136;
    char* rb0 = lds + 9728;

    for (int e = t; e < 160; e += 256) {
        int rt = e / 80, u = e % 80;
        int ph = u >> 2, g = u & 3;
        int pos = (ph < 6) ? ph : (56 + ph);
        *reinterpret_cast<s8v*>(lds + rt * 4864 + pos * 64 + ((g ^ ((pos >> 1) & 3)) << 4)) =
            (s8v)0;
    }
    for (int e = t; e < 112; e += 256) {
        int rt = e / 56, u = e % 56;
        int ph = u >> 2, g = u & 3;
        int pos = (ph < 3) ? ph : (56 + ph);
        *reinterpret_cast<s8v*>(rb0 + rt * 4480 + pos * 64 + ((g ^ ((pos >> 1) & 3)) << 4)) =
            (s8v)0;
    }
    for (int e = t; e < 896; e += 256) {
        int ci = e / 28, xq2 = e % 28;
        int rt = (xq2 >= 14) ? 1 : 0;
        int xq = xq2 - rt * 14;
        float sc = p2w[ci];
        float4 s = {0.f, 0.f, 0.f, 0.f};
#pragma unroll
        for (int k = 0; k < 3; ++k) {
            int yy = y0 - 3 + 3 * k + rt;
            if (yy < 0 || yy >= 56) continue;
            float wv = w5[ci * 3 + k] * sc;
            float4 vv = *(const float4*)(t1b + (size_t)ci * 3136 + (y0 - 3 + 3 * k) * 56 + xq2 * 4);
            s.x += wv * vv.x; s.y += wv * vv.y; s.z += wv * vv.z; s.w += wv * vv.w;
        }
        int g = ci >> 3, lo = (ci & 7) * 2;
        char* base = lds + rt * 4864;
#pragma unroll
        for (int j = 0; j < 4; ++j) {
            int pos = xq * 4 + j + 6;
            __hip_bfloat16 bv = __float2bfloat16(((const float*)&s)[j]);
            *(unsigned short*)(base + pos * 64 + ((g ^ ((pos >> 1) & 3)) << 4) + lo) =
                *(unsigned short*)&bv;
        }
    }
    __syncthreads();

    const char* sb = lds + rg * 4864;
    f32x4 acc[2][2];
    acc[0][0] = (f32x4)0.f; acc[0][1] = (f32x4)0.f;
    acc[1][0] = (f32x4)0.f; acc[1][1] = (f32x4)0.f;
#pragma unroll
    for (int j = 0; j < 7; ++j) {
        s8v af[2];
#pragma unroll
        for (int m = 0; m < 2; ++m)
            af[m] = *reinterpret_cast<const s8v*>(
                w8b + (size_t)(((j * 4 + h) * 32 + m * 16 + q) * 8));
#pragma unroll
        for (int nt = 0; nt < 2; ++nt) {
            int pos = (half * 2 + nt) * 16 + q + 2 * j;
            s8v bf = *reinterpret_cast<const s8v*>(sb + pos * 64 + ((h ^ ((pos >> 1) & 3)) << 4));
            acc[nt][0] = __builtin_amdgcn_mfma_f32_16x16x32_bf16(af[0], bf, acc[nt][0], 0, 0, 0);
            acc[nt][1] = __builtin_amdgcn_mfma_f32_16x16x32_bf16(af[1], bf, acc[nt][1], 0, 0, 0);
        }
    }

    char* rb = rb0 + rg * 4480;
#pragma unroll
    for (int nt = 0; nt < 2; ++nt) {
        int xx = (half * 2 + nt) * 16 + q;
        if (xx < 56) {
            int pos = xx + 3;
#pragma unroll
            for (int m = 0; m < 2; ++m)
#pragma unroll
                for (int r = 0; r < 4; ++r) {
                    int co = m * 16 + h * 4 + r;
                    __hip_bfloat16 bv = __float2bfloat16(acc[nt][m][r]);
                    *(unsigned short*)(rb + pos * 64 + (((co >> 3) ^ ((pos >> 1) & 3)) << 4) +
                                       (co & 7) * 2) = *(unsigned short*)&bv;
                }
        }
    }
    __syncthreads();
    for (int e = t; e < 560; e += 256) {
        int ridx = e / 280, u = e - ridx * 280;
        char* rowo = t8T + (size_t)(n * 56 + y0 + ridx) * 4480;
        *reinterpret_cast<s8v*>(rowo + u * 16) =
            *reinterpret_cast<const s8v*>(rb0 + ridx * 4480 + u * 16);
    }
}

// ---------------- L4: t8T -> t15 -> t16 + (pool->t11->t14 from t4) -> out ----------------
__global__ __launch_bounds__(512) void k_t15r(const char* __restrict__ t8T,
                                              const unsigned short* __restrict__ Wfb,
                                              const float* __restrict__ w16,
                                              const float* __restrict__ w14,
                                              const float* __restrict__ t4,
                                              float* __restrict__ out) {
    __shared__ __align__(16) char lds[18816];
    float* Rr   = (float*)(lds + 13440);
    float* Tt   = (float*)(lds + 14720);
    float* t14l = (float*)(lds + 15488);
    float* w16l = (float*)(lds + 15744);
    const int t = threadIdx.x;
    const int b = blockIdx.x;
    const int vb = (b & 7) * 224 + (b >> 3);
    const int n = vb / 56, y = vb % 56;
    const int l = t & 63, h = l >> 4, q = l & 15;
    const int w = t >> 6;
    const int co0 = w * 32;
    const float* t4b = t4 + (size_t)n * 3136;

    for (int e = t; e < 840; e += 512) {
        int ridx = e / 280, u = e - ridx * 280;
        int yy = y + 2 * ridx - 2;
        s8v v = (s8v)0;
        if (yy >= 0 && yy < 56)
            v = *reinterpret_cast<const s8v*>(t8T + (size_t)(n * 56 + yy) * 4480 + u * 16);
        *reinterpret_cast<s8v*>(lds + ridx * 4480 + u * 16) = v;
    }
    for (int e = t; e < 768; e += 512) w16l[e] = w16[e];
    for (int e = t; e < 280; e += 512) {
        int ridx = e / 56, xx = e % 56;
        int yc = y - 2 + ridx;
        float rv = 0.f;
        if (yc >= 0 && yc < 56) {
            float mm = -3.4e38f;
#pragma unroll
            for (int i = 0; i < 7; ++i) {
                int yy = yc + 3 * i - 9;
                float v = (yy >= 0 && yy < 56) ? t4b[(size_t)yy * 56 + xx] : 0.f;
                mm = fmaxf(mm, v);
            }
            rv = fmaxf(mm, 0.f);
        }
        Rr[ridx * 64 + xx] = rv;
    }
    __syncthreads();
    for (int e = t; e < 168; e += 512) {
        int ti = e / 56, px = e % 56;
        int yt = y - 1 + ti;
        float s = 0.f;
        if (yt >= 0 && yt < 56) {
#pragma unroll
            for (int dy = 0; dy < 3; ++dy) {
                int yr = yt + dy - 1;
                if (yr < 0 || yr >= 56) continue;
                int row = ti + dy;
#pragma unroll
                for (int j = 0; j < 7; ++j) {
                    int xx = px + 3 * j - 9;
                    if (xx >= 0 && xx < 56) s += Rr[row * 64 + xx];
                }
            }
            s *= (1.f / 21.f);
        }
        Tt[ti * 64 + px] = s;
    }
    __syncthreads();
    if (t < 56) {
        int px = t;
        float s = 0.f;
#pragma unroll
        for (int dy = 0; dy < 3; ++dy) {
            int yy = y + dy - 1;
            if (yy < 0 || yy >= 56) continue;
#pragma unroll
            for (int dx = 0; dx < 3; ++dx) {
                int xx = px + dx - 1;
                if (xx < 0 || xx >= 56) continue;
                s += Tt[dy * 64 + xx] * w14[dy * 3 + dx];
            }
        }
        t14l[px] = s;
    }
    __syncthreads();

    f32x4 acc[2][4];
#pragma unroll
    for (int m = 0; m < 2; ++m)
#pragma unroll
        for (int nt = 0; nt < 4; ++nt)
            acc[m][nt] = (f32x4)0.f;

#pragma unroll
    for (int dy = 0; dy < 3; ++dy) {
        const char* bbase = lds + dy * 4480;
#pragma unroll
        for (int dx = 0; dx < 7; ++dx) {
            const int kk = dy * 7 + dx;
            s8v af[2];
#pragma unroll
            for (int m = 0; m < 2; ++m)
                af[m] = *reinterpret_cast<const s8v*>(
                    Wfb + (size_t)kk * 8192 + (co0 + m * 16 + q) * 32 + h * 8);
            s8v bf[4];
#pragma unroll
            for (int nt = 0; nt < 4; ++nt) {
                int xp = nt * 16 + q + dx;
                bf[nt] = *reinterpret_cast<const s8v*>(
                    bbase + xp * 64 + ((h ^ ((xp >> 1) & 3)) << 4));
            }
#pragma unroll
            for (int nt = 0; nt < 4; ++nt)
#pragma unroll
                for (int m = 0; m < 2; ++m)
                    acc[m][nt] =
                        __builtin_amdgcn_mfma_f32_16x16x32_bf16(af[m], bf[nt], acc[m][nt], 0, 0, 0);
        }
    }

    float t14v[4];
#pragma unroll
    for (int nt = 0; nt < 4; ++nt) {
        int xx = nt * 16 + q;
        t14v[nt] = (xx < 56) ? t14l[xx] : 0.f;
    }
    const int srcm = (l & 48) | ((q + 13) & 15);
    const int srcp = (l & 48) | ((q + 3) & 15);
#pragma unroll
    for (int m = 0; m < 2; ++m) {
#pragma unroll
        for (int r = 0; r < 4; ++r) {
            int co = co0 + m * 16 + h * 4 + r;
            float wa = w16l[co * 3], wb = w16l[co * 3 + 1], wc = w16l[co * 3 + 2];
            float v[4], rm[4], rp[4];
#pragma unroll
            for (int nt = 0; nt < 4; ++nt) v[nt] = acc[m][nt][r];
#pragma unroll
            for (int nt = 0; nt < 4; ++nt) {
                rm[nt] = __shfl(v[nt], srcm, 64);
                rp[nt] = __shfl(v[nt], srcp, 64);
            }
            float* orow = out + ((size_t)(n * 256 + co) * 56 + y) * 56;
#pragma unroll
            for (int nt = 0; nt < 4; ++nt) {
                int xx = nt * 16 + q;
                float vm = (q >= 3) ? rm[nt] : (nt > 0 ? rm[nt - 1] : 0.f);
                float vp = (q < 13) ? rp[nt] : (nt < 3 ? rp[nt + 1] : 0.f);
                float s = v[nt] * wb + t14v[nt];
                s += (xx >= 3) ? vm * wa : 0.f;
                s += (xx <= 52) ? vp * wc : 0.f;
                if (xx < 56) orow[xx] = s;
            }
        }
    }
}

extern "C" void kernel_launch(void* const* d_in, const int* in_sizes, int n_in,
                              void* d_out, int out_size, void* d_ws, size_t ws_size,
                              hipStream_t stream) {
    const float* x   = (const float*)d_in[0];
    const float* w1  = (const float*)d_in[1];
    const float* p2w = (const float*)d_in[2];
    const float* w3  = (const float*)d_in[3];
    const float* w4  = (const float*)d_in[4];
    const float* w5  = (const float*)d_in[5];
    const float* w8  = (const float*)d_in[6];
    const float* w12 = (const float*)d_in[7];
    const float* w14 = (const float*)d_in[8];
    const float* w15 = (const float*)d_in[9];
    const float* w16 = (const float*)d_in[10];
    float* out = (float*)d_out;

    float* ws = (float*)d_ws;
    float* t1   = ws;                      // 3211264 f32
    char*  t8T  = (char*)(t1 + 3211264);   // 8,028,160 B
    float* t4   = t1 + 2 * 3211264;        // 100352 f32
    float* W34  = t4 + 100352;             // 288 f32
    __hip_bfloat16* Wfb = (__hip_bfloat16*)(W34 + 288);   // 172032 bf16
    __hip_bfloat16* w1b = Wfb + 172032;                   // 24576 bf16
    __hip_bfloat16* w8b = w1b + 24576;                    // 7168 bf16

    fuse_w1b<<<96, 256, 0, stream>>>(w1, w1b);
    k_t1f2<<<1024, 512, 0, stream>>>(x, (const unsigned short*)w1b, w3, w4, w8,
                                     t1, W34, w8b);
    k_mid<<<2016, 256, 0, stream>>>(t1, p2w, w5, (const unsigned short*)w8b,
                                    w15, w12, W34, t8T, Wfb, t4);
    k_t15r<<<1792, 512, 0, stream>>>(t8T, (const unsigned short*)Wfb, w16, w14, t4, out);
}